// Round 3
// baseline (836.003 us; speedup 1.0000x reference)
//
#include <hip/hip_runtime.h>
#include <hip/hip_bf16.h>

#define NN 100000
#define NE 1600000
#define NF 256
#define NC 40
#define NH 8
#define D1 64
#define NEG 0.2f

static __device__ __forceinline__ float lrelu(float x) { return x > 0.f ? x : NEG * x; }

// unpack a uint holding 2 bf16 (little-endian: low half = first elem) -> 2 floats
static __device__ __forceinline__ float2 bfx2(unsigned u) {
    union { unsigned q; float f; } a, b;
    a.q = u << 16;
    b.q = u & 0xFFFF0000u;
    return make_float2(a.f, b.f);
}

// pack 2 floats -> uint of 2 bf16, RNE
static __device__ __forceinline__ unsigned packbf2(float x, float y) {
    unsigned xu = __float_as_uint(x), yu = __float_as_uint(y);
    xu = (xu + 0x7FFFu + ((xu >> 16) & 1u)) >> 16;
    yu = (yu + 0x7FFFu + ((yu >> 16) & 1u)) >> 16;
    return xu | (yu << 16);
}

static __device__ __forceinline__ float b2f(unsigned short b) {
    union { unsigned q; float f; } a;
    a.q = ((unsigned)b) << 16;
    return a.f;
}

// ---------------- zero deg+fill (contiguous 2*NN ints) ----------------

__global__ void zero_k(int* __restrict__ p, int n) {
    int i = blockIdx.x * blockDim.x + threadIdx.x;
    if (i < n) p[i] = 0;
}

// ---------------- CSR build ----------------

__global__ void hist_k(const int* __restrict__ dst, int* __restrict__ deg) {
    int i = blockIdx.x * blockDim.x + threadIdx.x;
    if (i < NE) atomicAdd(&deg[dst[i]], 1);
}

__launch_bounds__(1024)
__global__ void scan_k(const int* __restrict__ deg, int* __restrict__ rowptr) {
    __shared__ int ps[1024];
    const int CHUNK = 98;  // ceil(100000/1024)
    int t = threadIdx.x;
    int start = t * CHUNK;
    int end = start + CHUNK; if (end > NN) end = NN;
    int s = 0;
    for (int i = start; i < end; ++i) s += deg[i];
    ps[t] = s;
    __syncthreads();
    for (int off = 1; off < 1024; off <<= 1) {
        int v = (t >= off) ? ps[t - off] : 0;
        __syncthreads();
        ps[t] += v;
        __syncthreads();
    }
    int run = (t == 0) ? 0 : ps[t - 1];
    for (int i = start; i < end; ++i) { rowptr[i] = run; run += deg[i]; }
    if (t == 1023) rowptr[NN] = ps[1023];
}

__global__ void scatter_k(const int* __restrict__ src, const int* __restrict__ dst,
                          const int* __restrict__ rowptr, int* __restrict__ fill, int* __restrict__ col) {
    int i = blockIdx.x * blockDim.x + threadIdx.x;
    if (i < NE) {
        int d = dst[i];
        int p = rowptr[d] + atomicAdd(&fill[d], 1);
        col[p] = src[i];
    }
}

// ---------------- GEMM1: h1 = x @ W1   [100000,256]x[256,64] -> bf16 ----------------

__launch_bounds__(256)
__global__ void gemm1_k(const float* __restrict__ x, const float* __restrict__ W,
                        unsigned short* __restrict__ h1b) {
    __shared__ float xs[64 * 68];
    __shared__ float ws[64 * 64];
    int r0 = blockIdx.x * 64;
    int tid = threadIdx.x;
    int tr = tid >> 4, tc = tid & 15;
    float acc[4][4] = {};
    for (int kt = 0; kt < 4; ++kt) {
        #pragma unroll
        for (int it = 0; it < 16; ++it) {
            int idx = tid + it * 256;
            int row = idx >> 6, kk = idx & 63;
            int gr = r0 + row;
            xs[row * 68 + kk] = (gr < NN) ? x[gr * NF + kt * 64 + kk] : 0.f;
        }
        #pragma unroll
        for (int it = 0; it < 16; ++it) {
            int idx = tid + it * 256;
            int k = idx >> 6, c = idx & 63;
            ws[k * 64 + c] = W[(kt * 64 + k) * 64 + c];
        }
        __syncthreads();
        #pragma unroll 4
        for (int k = 0; k < 64; ++k) {
            float a[4];
            #pragma unroll
            for (int j = 0; j < 4; ++j) a[j] = xs[(tr * 4 + j) * 68 + k];
            float4 bv = *(const float4*)&ws[k * 64 + tc * 4];
            float b[4] = {bv.x, bv.y, bv.z, bv.w};
            #pragma unroll
            for (int j = 0; j < 4; ++j)
                #pragma unroll
                for (int i = 0; i < 4; ++i)
                    acc[j][i] = fmaf(a[j], b[i], acc[j][i]);
        }
        __syncthreads();
    }
    #pragma unroll
    for (int j = 0; j < 4; ++j) {
        int gr = r0 + tr * 4 + j;
        if (gr < NN) {
            uint2 v;
            v.x = packbf2(acc[j][0], acc[j][1]);
            v.y = packbf2(acc[j][2], acc[j][3]);
            *(uint2*)&h1b[gr * D1 + tc * 4] = v;
        }
    }
}

// ---------------- attention coefficients layer 1 ----------------

__global__ void attn1_k(const unsigned short* __restrict__ h1b, const float* __restrict__ asrc,
                        const float* __restrict__ adst,
                        float* __restrict__ as1, float* __restrict__ ad1) {
    int t = blockIdx.x * blockDim.x + threadIdx.x;
    if (t >= NN * NH) return;
    int n = t >> 3, h = t & 7;
    uint4 v = *(const uint4*)&h1b[n * D1 + h * 8];
    float hv[8];
    float2 p;
    p = bfx2(v.x); hv[0] = p.x; hv[1] = p.y;
    p = bfx2(v.y); hv[2] = p.x; hv[3] = p.y;
    p = bfx2(v.z); hv[4] = p.x; hv[5] = p.y;
    p = bfx2(v.w); hv[6] = p.x; hv[7] = p.y;
    float sa = 0.f, sd = 0.f;
    #pragma unroll
    for (int c = 0; c < 8; ++c) {
        sa = fmaf(hv[c], asrc[h * 8 + c], sa);
        sd = fmaf(hv[c], adst[h * 8 + c], sd);
    }
    as1[t] = sa;
    ad1[t] = sd;
}

// ---------------- aggregation layer 1 (wave per node) + bias + ELU -> bf16 ----------------

__launch_bounds__(256)
__global__ void agg1_k(const unsigned short* __restrict__ h1b, const float* __restrict__ as1,
                       const float* __restrict__ ad1,
                       const int* __restrict__ rowptr, const int* __restrict__ col,
                       const float* __restrict__ b1, unsigned short* __restrict__ h1outb) {
    int n = blockIdx.x * 4 + (threadIdx.x >> 6);
    if (n >= NN) return;
    int lane = threadIdx.x & 63;
    int row0 = rowptr[n];
    int d = rowptr[n + 1] - row0;

    float ad[8];
    {
        float4 t0 = *(const float4*)&ad1[n * 8];
        float4 t1 = *(const float4*)&ad1[n * 8 + 4];
        ad[0] = t0.x; ad[1] = t0.y; ad[2] = t0.z; ad[3] = t0.w;
        ad[4] = t1.x; ad[5] = t1.y; ad[6] = t1.z; ad[7] = t1.w;
    }

    // phase A: per-head max
    float m[8];
    #pragma unroll
    for (int h = 0; h < 8; ++h) m[h] = -1e30f;
    for (int j = lane; j <= d; j += 64) {
        int s = (j < d) ? col[row0 + j] : n;
        float4 a0 = *(const float4*)&as1[s * 8];
        float4 a1 = *(const float4*)&as1[s * 8 + 4];
        float av[8] = {a0.x, a0.y, a0.z, a0.w, a1.x, a1.y, a1.z, a1.w};
        #pragma unroll
        for (int h = 0; h < 8; ++h) m[h] = fmaxf(m[h], lrelu(av[h] + ad[h]));
    }
    #pragma unroll
    for (int off = 32; off; off >>= 1)
        #pragma unroll
        for (int h = 0; h < 8; ++h) m[h] = fmaxf(m[h], __shfl_xor(m[h], off, 64));

    // phase B: per-head sum of exp
    float ssum[8] = {};
    for (int j = lane; j <= d; j += 64) {
        int s = (j < d) ? col[row0 + j] : n;
        float4 a0 = *(const float4*)&as1[s * 8];
        float4 a1 = *(const float4*)&as1[s * 8 + 4];
        float av[8] = {a0.x, a0.y, a0.z, a0.w, a1.x, a1.y, a1.z, a1.w};
        #pragma unroll
        for (int h = 0; h < 8; ++h) ssum[h] += __expf(lrelu(av[h] + ad[h]) - m[h]);
    }
    #pragma unroll
    for (int off = 32; off; off >>= 1)
        #pragma unroll
        for (int h = 0; h < 8; ++h) ssum[h] += __shfl_xor(ssum[h], off, 64);

    // phase C: weighted aggregation; lane owns channel `lane`, head = lane>>3
    int h = lane >> 3;
    float mh = m[h];
    float adh = ad[h];
    float inv = 1.f / (ssum[h] + 1e-16f);
    float acc = 0.f;
    for (int j = 0; j <= d; ++j) {
        int s = (j < d) ? col[row0 + j] : n;
        float e = lrelu(as1[s * 8 + h] + adh);
        float al = __expf(e - mh) * inv;
        acc = fmaf(b2f(h1b[s * D1 + lane]), al, acc);
    }
    float v = acc + b1[lane];
    v = (v > 0.f) ? v : (__expf(v) - 1.f);
    unsigned u = __float_as_uint(v);
    u = (u + 0x7FFFu + ((u >> 16) & 1u)) >> 16;
    h1outb[n * D1 + lane] = (unsigned short)u;
}

// ---------------- GEMM2: h2 = h1out @ W2   [100000,64]x[64,40] ----------------

__launch_bounds__(256)
__global__ void gemm2_k(const unsigned short* __restrict__ h1outb, const float* __restrict__ W2,
                        float* __restrict__ h2) {
    __shared__ float xs[64 * 68];
    __shared__ float ws[64 * 40];
    int r0 = blockIdx.x * 64;
    int tid = threadIdx.x;
    #pragma unroll
    for (int it = 0; it < 4; ++it) {
        int idx = tid + it * 256;       // 0..1023
        int row = idx >> 4;             // 0..63
        int q = (idx & 15) * 4;         // col quad base
        int gr = r0 + row;
        float f0 = 0.f, f1 = 0.f, f2 = 0.f, f3 = 0.f;
        if (gr < NN) {
            uint2 v = *(const uint2*)&h1outb[gr * D1 + q];
            float2 p0 = bfx2(v.x), p1 = bfx2(v.y);
            f0 = p0.x; f1 = p0.y; f2 = p1.x; f3 = p1.y;
        }
        xs[row * 68 + q] = f0;
        xs[row * 68 + q + 1] = f1;
        xs[row * 68 + q + 2] = f2;
        xs[row * 68 + q + 3] = f3;
    }
    #pragma unroll
    for (int it = 0; it < 10; ++it) {
        int idx = tid + it * 256;
        if (idx < 64 * 40) ws[idx] = W2[idx];
    }
    __syncthreads();
    int r = tid >> 2, q = tid & 3;
    float acc[10] = {};
    #pragma unroll 4
    for (int k = 0; k < 64; ++k) {
        float xv = xs[r * 68 + k];
        #pragma unroll
        for (int i = 0; i < 10; ++i)
            acc[i] = fmaf(xv, ws[k * 40 + q * 10 + i], acc[i]);
    }
    int gr = r0 + r;
    if (gr < NN) {
        #pragma unroll
        for (int i = 0; i < 10; ++i) h2[gr * NC + q * 10 + i] = acc[i];
    }
}

// ---------------- attention coefficients layer 2 ----------------

__global__ void attn2_k(const float* __restrict__ h2, const float* __restrict__ asrc,
                        const float* __restrict__ adst,
                        float* __restrict__ as2, float* __restrict__ ad2) {
    int n = blockIdx.x * blockDim.x + threadIdx.x;
    if (n >= NN) return;
    float sa = 0.f, sd = 0.f;
    #pragma unroll
    for (int c0 = 0; c0 < NC; c0 += 4) {
        float4 v = *(const float4*)&h2[n * NC + c0];
        float4 a = *(const float4*)&asrc[c0];
        float4 b = *(const float4*)&adst[c0];
        sa += v.x * a.x + v.y * a.y + v.z * a.z + v.w * a.w;
        sd += v.x * b.x + v.y * b.y + v.z * b.z + v.w * b.w;
    }
    as2[n] = sa;
    ad2[n] = sd;
}

// ---------------- aggregation layer 2 (wave per node) + bias -> out ----------------

__launch_bounds__(256)
__global__ void agg2_k(const float* __restrict__ h2, const float* __restrict__ as2,
                       const float* __restrict__ ad2,
                       const int* __restrict__ rowptr, const int* __restrict__ col,
                       const float* __restrict__ b2, float* __restrict__ out) {
    int n = blockIdx.x * 4 + (threadIdx.x >> 6);
    if (n >= NN) return;
    int lane = threadIdx.x & 63;
    int row0 = rowptr[n];
    int d = rowptr[n + 1] - row0;
    float adn = ad2[n];

    float m = -1e30f;
    for (int j = lane; j <= d; j += 64) {
        int s = (j < d) ? col[row0 + j] : n;
        m = fmaxf(m, lrelu(as2[s] + adn));
    }
    #pragma unroll
    for (int off = 32; off; off >>= 1) m = fmaxf(m, __shfl_xor(m, off, 64));

    float ss = 0.f;
    for (int j = lane; j <= d; j += 64) {
        int s = (j < d) ? col[row0 + j] : n;
        ss += __expf(lrelu(as2[s] + adn) - m);
    }
    #pragma unroll
    for (int off = 32; off; off >>= 1) ss += __shfl_xor(ss, off, 64);

    float inv = 1.f / (ss + 1e-16f);
    int cc = (lane < NC) ? lane : 0;
    float acc = 0.f;
    for (int j = 0; j <= d; ++j) {
        int s = (j < d) ? col[row0 + j] : n;
        float e = lrelu(as2[s] + adn);
        float al = __expf(e - m) * inv;
        acc = fmaf(h2[s * NC + cc], al, acc);
    }
    if (lane < NC) out[n * NC + lane] = acc + b2[lane];
}

// ---------------- launcher ----------------

extern "C" void kernel_launch(void* const* d_in, const int* in_sizes, int n_in,
                              void* d_out, int out_size, void* d_ws, size_t ws_size,
                              hipStream_t stream) {
    const float* x = (const float*)d_in[0];
    const int* ei = (const int*)d_in[1];   // harness passes integer inputs as int32!
    const int* src = ei;                   // edge_index row 0
    const int* dst = ei + NE;              // edge_index row 1
    const float* W1 = (const float*)d_in[2];
    const float* asrc1 = (const float*)d_in[3];
    const float* adst1 = (const float*)d_in[4];
    const float* b1 = (const float*)d_in[5];
    const float* W2 = (const float*)d_in[6];
    const float* asrc2 = (const float*)d_in[7];
    const float* adst2 = (const float*)d_in[8];
    const float* b2 = (const float*)d_in[9];
    float* out = (float*)d_out;

    // workspace layout (total 42,800,128 B):
    //   [0,16000000)          bufA: h1b bf16 (12.8MB) then h2 fp32 (16MB) after agg1
    //   [16000000,28800000)   h1outb bf16
    //   [28800000,32000000)   as1 fp32 (as2 aliases)
    //   [32000000,35200000)   ad1 fp32 (ad2 aliases)
    //   [35200000,41600000)   col int
    //   [41600000,42000128)   rowptr int (N+1, padded)
    //   [42000128,42400128)   deg int
    //   [42400128,42800128)   fill int
    char* ws = (char*)d_ws;
    unsigned short* h1b    = (unsigned short*)(ws + 0);
    float*          h2     = (float*)(ws + 0);
    unsigned short* h1outb = (unsigned short*)(ws + 16000000);
    float*          as1    = (float*)(ws + 28800000);
    float*          ad1    = (float*)(ws + 32000000);
    float*          as2    = as1;
    float*          ad2    = ad1;
    int*            col    = (int*)(ws + 35200000);
    int*            rowptr = (int*)(ws + 41600000);
    int*            deg    = (int*)(ws + 42000128);
    int*            fill   = (int*)(ws + 42400128);

    zero_k<<<(2 * NN + 255) / 256, 256, 0, stream>>>(deg, 2 * NN);  // deg+fill contiguous

    hist_k<<<(NE + 255) / 256, 256, 0, stream>>>(dst, deg);
    scan_k<<<1, 1024, 0, stream>>>(deg, rowptr);
    scatter_k<<<(NE + 255) / 256, 256, 0, stream>>>(src, dst, rowptr, fill, col);

    gemm1_k<<<(NN + 63) / 64, 256, 0, stream>>>(x, W1, h1b);
    attn1_k<<<(NN * NH + 255) / 256, 256, 0, stream>>>(h1b, asrc1, adst1, as1, ad1);
    agg1_k<<<(NN + 3) / 4, 256, 0, stream>>>(h1b, as1, ad1, rowptr, col, b1, h1outb);

    gemm2_k<<<(NN + 63) / 64, 256, 0, stream>>>(h1outb, W2, h2);
    attn2_k<<<(NN + 255) / 256, 256, 0, stream>>>(h2, asrc2, adst2, as2, ad2);
    agg2_k<<<(NN + 3) / 4, 256, 0, stream>>>(h2, as2, ad2, rowptr, col, b2, out);
}

// Round 4
// 563.822 us; speedup vs baseline: 1.4827x; 1.4827x over previous
//
#include <hip/hip_runtime.h>
#include <hip/hip_bf16.h>

#define NN 100000
#define NE 1600000
#define NF 256
#define NC 40
#define NH 8
#define D1 64
#define NEG 0.2f

static __device__ __forceinline__ float lrelu(float x) { return x > 0.f ? x : NEG * x; }

// unpack a uint holding 2 bf16 (little-endian: low half = first elem) -> 2 floats
static __device__ __forceinline__ float2 bfx2(unsigned u) {
    union { unsigned q; float f; } a, b;
    a.q = u << 16;
    b.q = u & 0xFFFF0000u;
    return make_float2(a.f, b.f);
}

// pack 2 floats -> uint of 2 bf16, RNE
static __device__ __forceinline__ unsigned packbf2(float x, float y) {
    unsigned xu = __float_as_uint(x), yu = __float_as_uint(y);
    xu = (xu + 0x7FFFu + ((xu >> 16) & 1u)) >> 16;
    yu = (yu + 0x7FFFu + ((yu >> 16) & 1u)) >> 16;
    return xu | (yu << 16);
}

// ---------------- zero deg+fill (contiguous 2*NN ints) ----------------

__global__ void zero_k(int* __restrict__ p, int n) {
    int i = blockIdx.x * blockDim.x + threadIdx.x;
    if (i < n) p[i] = 0;
}

// ---------------- CSR build ----------------

__global__ void hist_k(const int* __restrict__ dst, int* __restrict__ deg) {
    int i = blockIdx.x * blockDim.x + threadIdx.x;
    if (i < NE) atomicAdd(&deg[dst[i]], 1);
}

__launch_bounds__(1024)
__global__ void scan_k(const int* __restrict__ deg, int* __restrict__ rowptr) {
    __shared__ int ps[1024];
    const int CHUNK = 98;  // ceil(100000/1024)
    int t = threadIdx.x;
    int start = t * CHUNK;
    int end = start + CHUNK; if (end > NN) end = NN;
    int s = 0;
    for (int i = start; i < end; ++i) s += deg[i];
    ps[t] = s;
    __syncthreads();
    for (int off = 1; off < 1024; off <<= 1) {
        int v = (t >= off) ? ps[t - off] : 0;
        __syncthreads();
        ps[t] += v;
        __syncthreads();
    }
    int run = (t == 0) ? 0 : ps[t - 1];
    for (int i = start; i < end; ++i) { rowptr[i] = run; run += deg[i]; }
    if (t == 1023) rowptr[NN] = ps[1023];
}

__global__ void scatter_k(const int* __restrict__ src, const int* __restrict__ dst,
                          const int* __restrict__ rowptr, int* __restrict__ fill, int* __restrict__ col) {
    int i = blockIdx.x * blockDim.x + threadIdx.x;
    if (i < NE) {
        int d = dst[i];
        int p = rowptr[d] + atomicAdd(&fill[d], 1);
        col[p] = src[i];
    }
}

// ---------------- GEMM1: h1 = x @ W1   [100000,256]x[256,64] -> bf16 ----------------

__launch_bounds__(256)
__global__ void gemm1_k(const float* __restrict__ x, const float* __restrict__ W,
                        unsigned short* __restrict__ h1b) {
    __shared__ float xs[64 * 68];
    __shared__ float ws[64 * 64];
    int r0 = blockIdx.x * 64;
    int tid = threadIdx.x;
    int tr = tid >> 4, tc = tid & 15;
    float acc[4][4] = {};
    for (int kt = 0; kt < 4; ++kt) {
        #pragma unroll
        for (int it = 0; it < 16; ++it) {
            int idx = tid + it * 256;
            int row = idx >> 6, kk = idx & 63;
            int gr = r0 + row;
            xs[row * 68 + kk] = (gr < NN) ? x[gr * NF + kt * 64 + kk] : 0.f;
        }
        #pragma unroll
        for (int it = 0; it < 16; ++it) {
            int idx = tid + it * 256;
            int k = idx >> 6, c = idx & 63;
            ws[k * 64 + c] = W[(kt * 64 + k) * 64 + c];
        }
        __syncthreads();
        #pragma unroll 4
        for (int k = 0; k < 64; ++k) {
            float a[4];
            #pragma unroll
            for (int j = 0; j < 4; ++j) a[j] = xs[(tr * 4 + j) * 68 + k];
            float4 bv = *(const float4*)&ws[k * 64 + tc * 4];
            float b[4] = {bv.x, bv.y, bv.z, bv.w};
            #pragma unroll
            for (int j = 0; j < 4; ++j)
                #pragma unroll
                for (int i = 0; i < 4; ++i)
                    acc[j][i] = fmaf(a[j], b[i], acc[j][i]);
        }
        __syncthreads();
    }
    #pragma unroll
    for (int j = 0; j < 4; ++j) {
        int gr = r0 + tr * 4 + j;
        if (gr < NN) {
            uint2 v;
            v.x = packbf2(acc[j][0], acc[j][1]);
            v.y = packbf2(acc[j][2], acc[j][3]);
            *(uint2*)&h1b[gr * D1 + tc * 4] = v;
        }
    }
}

// ---------------- attention coefficients layer 1 ----------------

__global__ void attn1_k(const unsigned short* __restrict__ h1b, const float* __restrict__ asrc,
                        const float* __restrict__ adst,
                        float* __restrict__ as1, float* __restrict__ ad1) {
    int t = blockIdx.x * blockDim.x + threadIdx.x;
    if (t >= NN * NH) return;
    int n = t >> 3, h = t & 7;
    uint4 v = *(const uint4*)&h1b[n * D1 + h * 8];
    float hv[8];
    float2 p;
    p = bfx2(v.x); hv[0] = p.x; hv[1] = p.y;
    p = bfx2(v.y); hv[2] = p.x; hv[3] = p.y;
    p = bfx2(v.z); hv[4] = p.x; hv[5] = p.y;
    p = bfx2(v.w); hv[6] = p.x; hv[7] = p.y;
    float sa = 0.f, sd = 0.f;
    #pragma unroll
    for (int c = 0; c < 8; ++c) {
        sa = fmaf(hv[c], asrc[h * 8 + c], sa);
        sd = fmaf(hv[c], adst[h * 8 + c], sd);
    }
    as1[t] = sa;
    ad1[t] = sd;
}

// ---------------- aggregation layer 1: single fused pass, 8 edges in flight ----------------
// wave = 8 groups x 8 lanes. group g handles edges j+g; lane ln handles head ln,
// channels ln*8..ln*8+7. No max-subtraction (logits bounded; exp(e)/sum identical).

__launch_bounds__(256)
__global__ void agg1_k(const unsigned short* __restrict__ h1b, const float* __restrict__ as1,
                       const float* __restrict__ ad1,
                       const int* __restrict__ rowptr, const int* __restrict__ col,
                       const float* __restrict__ b1, unsigned short* __restrict__ h1outb) {
    int n = blockIdx.x * 4 + (threadIdx.x >> 6);
    if (n >= NN) return;
    int lane = threadIdx.x & 63;
    int g = lane >> 3, ln = lane & 7;
    int row0 = rowptr[n];
    int d = rowptr[n + 1] - row0;
    float adh = ad1[n * 8 + ln];

    float acc[8] = {};
    float wsum = 0.f;
    for (int j = 0; j <= d; j += 8) {
        int jj = j + g;
        int s = (jj < d) ? col[row0 + jj] : n;   // virtual self-loop at jj==d
        float e = lrelu(as1[s * 8 + ln] + adh);
        float wgt = (jj <= d) ? __expf(e) : 0.f;
        wsum += wgt;
        uint4 hv = *(const uint4*)&h1b[s * D1 + ln * 8];
        float2 p;
        p = bfx2(hv.x); acc[0] = fmaf(p.x, wgt, acc[0]); acc[1] = fmaf(p.y, wgt, acc[1]);
        p = bfx2(hv.y); acc[2] = fmaf(p.x, wgt, acc[2]); acc[3] = fmaf(p.y, wgt, acc[3]);
        p = bfx2(hv.z); acc[4] = fmaf(p.x, wgt, acc[4]); acc[5] = fmaf(p.y, wgt, acc[5]);
        p = bfx2(hv.w); acc[6] = fmaf(p.x, wgt, acc[6]); acc[7] = fmaf(p.y, wgt, acc[7]);
    }
    // reduce across the 8 groups (lane bits 3..5)
    #pragma unroll
    for (int off = 8; off <= 32; off <<= 1) {
        wsum += __shfl_xor(wsum, off, 64);
        #pragma unroll
        for (int k = 0; k < 8; ++k) acc[k] += __shfl_xor(acc[k], off, 64);
    }
    if (g == 0) {
        float inv = 1.f / (wsum + 1e-16f);
        unsigned u[4];
        #pragma unroll
        for (int k = 0; k < 4; ++k) {
            float v0 = fmaf(acc[2 * k], inv, b1[ln * 8 + 2 * k]);
            float v1 = fmaf(acc[2 * k + 1], inv, b1[ln * 8 + 2 * k + 1]);
            v0 = (v0 > 0.f) ? v0 : (__expf(v0) - 1.f);   // ELU
            v1 = (v1 > 0.f) ? v1 : (__expf(v1) - 1.f);
            u[k] = packbf2(v0, v1);
        }
        uint4 w = {u[0], u[1], u[2], u[3]};
        *(uint4*)&h1outb[n * D1 + ln * 8] = w;
    }
}

// ---------------- GEMM2: h2p = h1out @ W2, padded [N][64] (cols 40..63 = 0) ----------------

__launch_bounds__(256)
__global__ void gemm2_k(const unsigned short* __restrict__ h1outb, const float* __restrict__ W2,
                        float* __restrict__ h2p) {
    __shared__ float xs[64 * 68];
    __shared__ float ws[64 * 40];
    int r0 = blockIdx.x * 64;
    int tid = threadIdx.x;
    #pragma unroll
    for (int it = 0; it < 4; ++it) {
        int idx = tid + it * 256;       // 0..1023
        int row = idx >> 4;             // 0..63
        int q = (idx & 15) * 4;         // col quad base
        int gr = r0 + row;
        float f0 = 0.f, f1 = 0.f, f2 = 0.f, f3 = 0.f;
        if (gr < NN) {
            uint2 v = *(const uint2*)&h1outb[gr * D1 + q];
            float2 p0 = bfx2(v.x), p1 = bfx2(v.y);
            f0 = p0.x; f1 = p0.y; f2 = p1.x; f3 = p1.y;
        }
        xs[row * 68 + q] = f0;
        xs[row * 68 + q + 1] = f1;
        xs[row * 68 + q + 2] = f2;
        xs[row * 68 + q + 3] = f3;
    }
    #pragma unroll
    for (int it = 0; it < 10; ++it) {
        int idx = tid + it * 256;
        if (idx < 64 * 40) ws[idx] = W2[idx];
    }
    __syncthreads();
    int r = tid >> 2, q = tid & 3;
    float acc[10] = {};
    #pragma unroll 4
    for (int k = 0; k < 64; ++k) {
        float xv = xs[r * 68 + k];
        #pragma unroll
        for (int i = 0; i < 10; ++i)
            acc[i] = fmaf(xv, ws[k * 40 + q * 10 + i], acc[i]);
    }
    int gr = r0 + r;
    if (gr < NN) {
        #pragma unroll
        for (int i = 0; i < 10; ++i) h2p[gr * 64 + q * 10 + i] = acc[i];
    }
    // zero pad columns 40..63
    for (int idx = tid; idx < 64 * 24; idx += 256) {
        int row = idx / 24, c = 40 + idx % 24;
        int g2 = r0 + row;
        if (g2 < NN) h2p[g2 * 64 + c] = 0.f;
    }
}

// ---------------- attention coefficients layer 2 ----------------

__global__ void attn2_k(const float* __restrict__ h2p, const float* __restrict__ asrc,
                        const float* __restrict__ adst,
                        float* __restrict__ as2, float* __restrict__ ad2) {
    int n = blockIdx.x * blockDim.x + threadIdx.x;
    if (n >= NN) return;
    float sa = 0.f, sd = 0.f;
    #pragma unroll
    for (int c0 = 0; c0 < NC; c0 += 4) {
        float4 v = *(const float4*)&h2p[n * 64 + c0];
        float4 a = *(const float4*)&asrc[c0];
        float4 b = *(const float4*)&adst[c0];
        sa += v.x * a.x + v.y * a.y + v.z * a.z + v.w * a.w;
        sd += v.x * b.x + v.y * b.y + v.z * b.z + v.w * b.w;
    }
    as2[n] = sa;
    ad2[n] = sd;
}

// ---------------- aggregation layer 2: fused single pass, 8 edges in flight ----------------

__launch_bounds__(256)
__global__ void agg2_k(const float* __restrict__ h2p, const float* __restrict__ as2,
                       const float* __restrict__ ad2,
                       const int* __restrict__ rowptr, const int* __restrict__ col,
                       const float* __restrict__ b2, float* __restrict__ out) {
    int n = blockIdx.x * 4 + (threadIdx.x >> 6);
    if (n >= NN) return;
    int lane = threadIdx.x & 63;
    int g = lane >> 3, ln = lane & 7;
    int row0 = rowptr[n];
    int d = rowptr[n + 1] - row0;
    float adn = ad2[n];

    float acc[8] = {};
    float wsum = 0.f;
    for (int j = 0; j <= d; j += 8) {
        int jj = j + g;
        int s = (jj < d) ? col[row0 + jj] : n;
        float e = lrelu(as2[s] + adn);
        float wgt = (jj <= d) ? __expf(e) : 0.f;
        wsum += wgt;
        float4 v0 = *(const float4*)&h2p[s * 64 + ln * 8];
        float4 v1 = *(const float4*)&h2p[s * 64 + ln * 8 + 4];
        acc[0] = fmaf(v0.x, wgt, acc[0]); acc[1] = fmaf(v0.y, wgt, acc[1]);
        acc[2] = fmaf(v0.z, wgt, acc[2]); acc[3] = fmaf(v0.w, wgt, acc[3]);
        acc[4] = fmaf(v1.x, wgt, acc[4]); acc[5] = fmaf(v1.y, wgt, acc[5]);
        acc[6] = fmaf(v1.z, wgt, acc[6]); acc[7] = fmaf(v1.w, wgt, acc[7]);
    }
    // reduce across groups; wsum is replicated per-group so this yields the full node sum
    #pragma unroll
    for (int off = 8; off <= 32; off <<= 1) {
        wsum += __shfl_xor(wsum, off, 64);
        #pragma unroll
        for (int k = 0; k < 8; ++k) acc[k] += __shfl_xor(acc[k], off, 64);
    }
    if (g == 0 && ln < 5) {   // channels ln*8..ln*8+7, only 0..39 valid
        float inv = 1.f / (wsum * 0.125f + 1e-16f);   // wsum was summed over 8 identical lane copies
        float4 o0, o1;
        o0.x = fmaf(acc[0] * 0.125f, inv * 0.125f * 8.f, b2[ln * 8 + 0]);
        // (see note) -- compute plainly below instead
        o0.x = fmaf(acc[0], inv * 0.125f, b2[ln * 8 + 0]);
        o0.y = fmaf(acc[1], inv * 0.125f, b2[ln * 8 + 1]);
        o0.z = fmaf(acc[2], inv * 0.125f, b2[ln * 8 + 2]);
        o0.w = fmaf(acc[3], inv * 0.125f, b2[ln * 8 + 3]);
        o1.x = fmaf(acc[4], inv * 0.125f, b2[ln * 8 + 4]);
        o1.y = fmaf(acc[5], inv * 0.125f, b2[ln * 8 + 5]);
        o1.z = fmaf(acc[6], inv * 0.125f, b2[ln * 8 + 6]);
        o1.w = fmaf(acc[7], inv * 0.125f, b2[ln * 8 + 7]);
        *(float4*)&out[n * NC + ln * 8] = o0;
        *(float4*)&out[n * NC + ln * 8 + 4] = o1;
    }
}
// note: in agg2, each of the 8 lanes of a group accumulates the SAME wgt (single head),
// so the group-reduced wsum is 8x the true per-node sum -> scale by 0.125 before inverting.
// acc channels are NOT replicated (each lane owns distinct channels), so acc is exact.

// ---------------- launcher ----------------

extern "C" void kernel_launch(void* const* d_in, const int* in_sizes, int n_in,
                              void* d_out, int out_size, void* d_ws, size_t ws_size,
                              hipStream_t stream) {
    const float* x = (const float*)d_in[0];
    const int* ei = (const int*)d_in[1];   // harness passes integer inputs as int32
    const int* src = ei;
    const int* dst = ei + NE;
    const float* W1 = (const float*)d_in[2];
    const float* asrc1 = (const float*)d_in[3];
    const float* adst1 = (const float*)d_in[4];
    const float* b1 = (const float*)d_in[5];
    const float* W2 = (const float*)d_in[6];
    const float* asrc2 = (const float*)d_in[7];
    const float* adst2 = (const float*)d_in[8];
    const float* b2 = (const float*)d_in[9];
    float* out = (float*)d_out;

    // workspace layout (total 46,800,128 B):
    //   [0,12800000)           h1b bf16 [N][64]
    //   [12800000,16000000)    as1 fp32 [N][8]
    //   [16000000,19200000)    ad1 fp32 [N][8]
    //   [0,25600000)           h2p fp32 [N][64]  (aliases h1b/as1/ad1 -- dead after agg1)
    //   [25600000,38400000)    h1outb bf16 [N][64]
    //   [38400000,38800000)    as2 fp32 [N]
    //   [38800000,39200000)    ad2 fp32 [N]
    //   [39200000,45600000)    col int [NE]
    //   [45600000,46000128)    rowptr int [N+1, padded]
    //   [46000128,46400128)    deg int [N]
    //   [46400128,46800128)    fill int [N]
    char* ws = (char*)d_ws;
    unsigned short* h1b    = (unsigned short*)(ws + 0);
    float*          as1    = (float*)(ws + 12800000);
    float*          ad1    = (float*)(ws + 16000000);
    float*          h2p    = (float*)(ws + 0);
    unsigned short* h1outb = (unsigned short*)(ws + 25600000);
    float*          as2    = (float*)(ws + 38400000);
    float*          ad2    = (float*)(ws + 38800000);
    int*            col    = (int*)(ws + 39200000);
    int*            rowptr = (int*)(ws + 45600000);
    int*            deg    = (int*)(ws + 46000128);
    int*            fill   = (int*)(ws + 46400128);

    zero_k<<<(2 * NN + 255) / 256, 256, 0, stream>>>(deg, 2 * NN);  // deg+fill contiguous

    hist_k<<<(NE + 255) / 256, 256, 0, stream>>>(dst, deg);
    scan_k<<<1, 1024, 0, stream>>>(deg, rowptr);
    scatter_k<<<(NE + 255) / 256, 256, 0, stream>>>(src, dst, rowptr, fill, col);

    gemm1_k<<<(NN + 63) / 64, 256, 0, stream>>>(x, W1, h1b);
    attn1_k<<<(NN * NH + 255) / 256, 256, 0, stream>>>(h1b, asrc1, adst1, as1, ad1);
    agg1_k<<<(NN + 3) / 4, 256, 0, stream>>>(h1b, as1, ad1, rowptr, col, b1, h1outb);

    gemm2_k<<<(NN + 63) / 64, 256, 0, stream>>>(h1outb, W2, h2p);
    attn2_k<<<(NN + 255) / 256, 256, 0, stream>>>(h2p, asrc2, adst2, as2, ad2);
    agg2_k<<<(NN + 3) / 4, 256, 0, stream>>>(h2p, as2, ad2, rowptr, col, b2, out);
}

// Round 6
// 402.941 us; speedup vs baseline: 2.0748x; 1.3993x over previous
//
#include <hip/hip_runtime.h>
#include <hip/hip_bf16.h>

#define NN 100000
#define NE 1600000
#define NF 256
#define NC 40
#define NH 8
#define D1 64
#define NEG 0.2f
#define SCAN_B 98   // ceil(NN / 1024)

static __device__ __forceinline__ float lrelu(float x) { return x > 0.f ? x : NEG * x; }

// unpack a uint holding 2 bf16 (little-endian: low half = first elem) -> 2 floats
static __device__ __forceinline__ float2 bfx2(unsigned u) {
    union { unsigned q; float f; } a, b;
    a.q = u << 16;
    b.q = u & 0xFFFF0000u;
    return make_float2(a.f, b.f);
}

// pack 2 floats -> uint of 2 bf16, RNE
static __device__ __forceinline__ unsigned packbf2(float x, float y) {
    unsigned xu = __float_as_uint(x), yu = __float_as_uint(y);
    xu = (xu + 0x7FFFu + ((xu >> 16) & 1u)) >> 16;
    yu = (yu + 0x7FFFu + ((yu >> 16) & 1u)) >> 16;
    return xu | (yu << 16);
}

// ---------------- zero deg+fill (contiguous 2*NN ints) ----------------

__global__ void zero_k(int* __restrict__ p, int n) {
    int i = blockIdx.x * blockDim.x + threadIdx.x;
    if (i < n) p[i] = 0;
}

// ---------------- CSR build ----------------

__global__ void hist_k(const int* __restrict__ dst, int* __restrict__ deg) {
    int i = blockIdx.x * blockDim.x + threadIdx.x;
    if (i < NE) atomicAdd(&deg[dst[i]], 1);
}

// device-wide scan, step 1: per-block scan of 1024 elements (256 thr x 4)
__launch_bounds__(256)
__global__ void scan1_k(const int* __restrict__ deg, int* __restrict__ rowptr, int* __restrict__ bsum) {
    __shared__ int ts[256];
    int b = blockIdx.x, t = threadIdx.x;
    int base = b * 1024 + t * 4;
    int v0 = 0, v1 = 0, v2 = 0, v3 = 0;
    if (base + 3 < NN) {
        int4 q = *(const int4*)&deg[base];
        v0 = q.x; v1 = q.y; v2 = q.z; v3 = q.w;
    } else {
        if (base < NN)     v0 = deg[base];
        if (base + 1 < NN) v1 = deg[base + 1];
        if (base + 2 < NN) v2 = deg[base + 2];
        if (base + 3 < NN) v3 = deg[base + 3];
    }
    int tot = v0 + v1 + v2 + v3;
    ts[t] = tot;
    __syncthreads();
    #pragma unroll
    for (int off = 1; off < 256; off <<= 1) {
        int x = (t >= off) ? ts[t - off] : 0;
        __syncthreads();
        ts[t] += x;
        __syncthreads();
    }
    int ex = ts[t] - tot;  // exclusive prefix of this thread within the block
    if (base < NN)     rowptr[base]     = ex;
    if (base + 1 < NN) rowptr[base + 1] = ex + v0;
    if (base + 2 < NN) rowptr[base + 2] = ex + v0 + v1;
    if (base + 3 < NN) rowptr[base + 3] = ex + v0 + v1 + v2;
    if (t == 255) bsum[b] = ts[255];
}

// step 2: scan the 98 block sums (one small block)
__launch_bounds__(128)
__global__ void scan2_k(const int* __restrict__ bsum, int* __restrict__ boff) {
    __shared__ int s[128];
    int t = threadIdx.x;
    int v = (t < SCAN_B) ? bsum[t] : 0;
    s[t] = v;
    __syncthreads();
    #pragma unroll
    for (int off = 1; off < 128; off <<= 1) {
        int x = (t >= off) ? s[t - off] : 0;
        __syncthreads();
        s[t] += x;
        __syncthreads();
    }
    if (t < SCAN_B) boff[t] = s[t] - v;  // exclusive
}

// step 3: add block offsets; set rowptr[NN]
__launch_bounds__(256)
__global__ void scan3_k(int* __restrict__ rowptr, const int* __restrict__ boff) {
    int b = blockIdx.x, t = threadIdx.x;
    int off = boff[b];
    int base = b * 1024 + t * 4;
    if (base + 3 < NN) {
        int4* p = (int4*)&rowptr[base];
        int4 q = *p;
        q.x += off; q.y += off; q.z += off; q.w += off;
        *p = q;
    } else {
        #pragma unroll
        for (int k = 0; k < 4; ++k) if (base + k < NN) rowptr[base + k] += off;
    }
    if (b == 0 && t == 0) rowptr[NN] = NE;  // every edge counted exactly once
}

__global__ void scatter_k(const int* __restrict__ src, const int* __restrict__ dst,
                          const int* __restrict__ rowptr, int* __restrict__ fill, int* __restrict__ col) {
    int i = blockIdx.x * blockDim.x + threadIdx.x;
    if (i < NE) {
        int d = dst[i];
        int p = rowptr[d] + atomicAdd(&fill[d], 1);
        col[p] = src[i];
    }
}

// ---------------- GEMM1: h1 = x @ W1   [100000,256]x[256,64] -> bf16 ----------------

__launch_bounds__(256)
__global__ void gemm1_k(const float* __restrict__ x, const float* __restrict__ W,
                        unsigned short* __restrict__ h1b) {
    __shared__ float xs[64 * 68];
    __shared__ float ws[64 * 64];
    int r0 = blockIdx.x * 64;
    int tid = threadIdx.x;
    int tr = tid >> 4, tc = tid & 15;
    float acc[4][4] = {};
    for (int kt = 0; kt < 4; ++kt) {
        #pragma unroll
        for (int it = 0; it < 16; ++it) {
            int idx = tid + it * 256;
            int row = idx >> 6, kk = idx & 63;
            int gr = r0 + row;
            xs[row * 68 + kk] = (gr < NN) ? x[gr * NF + kt * 64 + kk] : 0.f;
        }
        #pragma unroll
        for (int it = 0; it < 16; ++it) {
            int idx = tid + it * 256;
            int k = idx >> 6, c = idx & 63;
            ws[k * 64 + c] = W[(kt * 64 + k) * 64 + c];
        }
        __syncthreads();
        #pragma unroll 4
        for (int k = 0; k < 64; ++k) {
            float a[4];
            #pragma unroll
            for (int j = 0; j < 4; ++j) a[j] = xs[(tr * 4 + j) * 68 + k];
            float4 bv = *(const float4*)&ws[k * 64 + tc * 4];
            float b[4] = {bv.x, bv.y, bv.z, bv.w};
            #pragma unroll
            for (int j = 0; j < 4; ++j)
                #pragma unroll
                for (int i = 0; i < 4; ++i)
                    acc[j][i] = fmaf(a[j], b[i], acc[j][i]);
        }
        __syncthreads();
    }
    #pragma unroll
    for (int j = 0; j < 4; ++j) {
        int gr = r0 + tr * 4 + j;
        if (gr < NN) {
            uint2 v;
            v.x = packbf2(acc[j][0], acc[j][1]);
            v.y = packbf2(acc[j][2], acc[j][3]);
            *(uint2*)&h1b[gr * D1 + tc * 4] = v;
        }
    }
}

// ---------------- attention coefficients layer 1 ----------------

__global__ void attn1_k(const unsigned short* __restrict__ h1b, const float* __restrict__ asrc,
                        const float* __restrict__ adst,
                        float* __restrict__ as1, float* __restrict__ ad1) {
    int t = blockIdx.x * blockDim.x + threadIdx.x;
    if (t >= NN * NH) return;
    int n = t >> 3, h = t & 7;
    uint4 v = *(const uint4*)&h1b[n * D1 + h * 8];
    float hv[8];
    float2 p;
    p = bfx2(v.x); hv[0] = p.x; hv[1] = p.y;
    p = bfx2(v.y); hv[2] = p.x; hv[3] = p.y;
    p = bfx2(v.z); hv[4] = p.x; hv[5] = p.y;
    p = bfx2(v.w); hv[6] = p.x; hv[7] = p.y;
    float sa = 0.f, sd = 0.f;
    #pragma unroll
    for (int c = 0; c < 8; ++c) {
        sa = fmaf(hv[c], asrc[h * 8 + c], sa);
        sd = fmaf(hv[c], adst[h * 8 + c], sd);
    }
    as1[t] = sa;
    ad1[t] = sd;
}

// ---------------- aggregation layer 1: single fused pass, 8 edges in flight ----------------

__launch_bounds__(256)
__global__ void agg1_k(const unsigned short* __restrict__ h1b, const float* __restrict__ as1,
                       const float* __restrict__ ad1,
                       const int* __restrict__ rowptr, const int* __restrict__ col,
                       const float* __restrict__ b1, unsigned short* __restrict__ h1outb) {
    int n = blockIdx.x * 4 + (threadIdx.x >> 6);
    if (n >= NN) return;
    int lane = threadIdx.x & 63;
    int g = lane >> 3, ln = lane & 7;
    int row0 = rowptr[n];
    int d = rowptr[n + 1] - row0;
    float adh = ad1[n * 8 + ln];

    float acc[8] = {};
    float wsum = 0.f;
    for (int j = 0; j <= d; j += 8) {
        int jj = j + g;
        int s = (jj < d) ? col[row0 + jj] : n;   // virtual self-loop at jj==d
        float e = lrelu(as1[s * 8 + ln] + adh);
        float wgt = (jj <= d) ? __expf(e) : 0.f;
        wsum += wgt;
        uint4 hv = *(const uint4*)&h1b[s * D1 + ln * 8];
        float2 p;
        p = bfx2(hv.x); acc[0] = fmaf(p.x, wgt, acc[0]); acc[1] = fmaf(p.y, wgt, acc[1]);
        p = bfx2(hv.y); acc[2] = fmaf(p.x, wgt, acc[2]); acc[3] = fmaf(p.y, wgt, acc[3]);
        p = bfx2(hv.z); acc[4] = fmaf(p.x, wgt, acc[4]); acc[5] = fmaf(p.y, wgt, acc[5]);
        p = bfx2(hv.w); acc[6] = fmaf(p.x, wgt, acc[6]); acc[7] = fmaf(p.y, wgt, acc[7]);
    }
    #pragma unroll
    for (int off = 8; off <= 32; off <<= 1) {
        wsum += __shfl_xor(wsum, off, 64);
        #pragma unroll
        for (int k = 0; k < 8; ++k) acc[k] += __shfl_xor(acc[k], off, 64);
    }
    if (g == 0) {
        float inv = 1.f / (wsum + 1e-16f);
        unsigned u[4];
        #pragma unroll
        for (int k = 0; k < 4; ++k) {
            float v0 = fmaf(acc[2 * k], inv, b1[ln * 8 + 2 * k]);
            float v1 = fmaf(acc[2 * k + 1], inv, b1[ln * 8 + 2 * k + 1]);
            v0 = (v0 > 0.f) ? v0 : (__expf(v0) - 1.f);   // ELU
            v1 = (v1 > 0.f) ? v1 : (__expf(v1) - 1.f);
            u[k] = packbf2(v0, v1);
        }
        uint4 w = {u[0], u[1], u[2], u[3]};
        *(uint4*)&h1outb[n * D1 + ln * 8] = w;
    }
}

// ---------------- GEMM2: h2p = h1out @ W2, padded [N][64] (cols 40..63 = 0) ----------------

__launch_bounds__(256)
__global__ void gemm2_k(const unsigned short* __restrict__ h1outb, const float* __restrict__ W2,
                        float* __restrict__ h2p) {
    __shared__ float xs[64 * 68];
    __shared__ float ws[64 * 40];
    int r0 = blockIdx.x * 64;
    int tid = threadIdx.x;
    #pragma unroll
    for (int it = 0; it < 4; ++it) {
        int idx = tid + it * 256;       // 0..1023
        int row = idx >> 4;             // 0..63
        int q = (idx & 15) * 4;         // col quad base
        int gr = r0 + row;
        float f0 = 0.f, f1 = 0.f, f2 = 0.f, f3 = 0.f;
        if (gr < NN) {
            uint2 v = *(const uint2*)&h1outb[gr * D1 + q];
            float2 p0 = bfx2(v.x), p1 = bfx2(v.y);
            f0 = p0.x; f1 = p0.y; f2 = p1.x; f3 = p1.y;
        }
        xs[row * 68 + q] = f0;
        xs[row * 68 + q + 1] = f1;
        xs[row * 68 + q + 2] = f2;
        xs[row * 68 + q + 3] = f3;
    }
    #pragma unroll
    for (int it = 0; it < 10; ++it) {
        int idx = tid + it * 256;
        if (idx < 64 * 40) ws[idx] = W2[idx];
    }
    __syncthreads();
    int r = tid >> 2, q = tid & 3;
    float acc[10] = {};
    #pragma unroll 4
    for (int k = 0; k < 64; ++k) {
        float xv = xs[r * 68 + k];
        #pragma unroll
        for (int i = 0; i < 10; ++i)
            acc[i] = fmaf(xv, ws[k * 40 + q * 10 + i], acc[i]);
    }
    int gr = r0 + r;
    if (gr < NN) {
        #pragma unroll
        for (int i = 0; i < 10; ++i) h2p[gr * 64 + q * 10 + i] = acc[i];
    }
    // zero pad columns 40..63
    for (int idx = tid; idx < 64 * 24; idx += 256) {
        int row = idx / 24, c = 40 + idx % 24;
        int g2 = r0 + row;
        if (g2 < NN) h2p[g2 * 64 + c] = 0.f;
    }
}

// ---------------- attention coefficients layer 2 ----------------

__global__ void attn2_k(const float* __restrict__ h2p, const float* __restrict__ asrc,
                        const float* __restrict__ adst,
                        float* __restrict__ as2, float* __restrict__ ad2) {
    int n = blockIdx.x * blockDim.x + threadIdx.x;
    if (n >= NN) return;
    float sa = 0.f, sd = 0.f;
    #pragma unroll
    for (int c0 = 0; c0 < NC; c0 += 4) {
        float4 v = *(const float4*)&h2p[n * 64 + c0];
        float4 a = *(const float4*)&asrc[c0];
        float4 b = *(const float4*)&adst[c0];
        sa += v.x * a.x + v.y * a.y + v.z * a.z + v.w * a.w;
        sd += v.x * b.x + v.y * b.y + v.z * b.z + v.w * b.w;
    }
    as2[n] = sa;
    ad2[n] = sd;
}

// ---------------- aggregation layer 2: fused single pass, 8 edges in flight ----------------

__launch_bounds__(256)
__global__ void agg2_k(const float* __restrict__ h2p, const float* __restrict__ as2,
                       const float* __restrict__ ad2,
                       const int* __restrict__ rowptr, const int* __restrict__ col,
                       const float* __restrict__ b2, float* __restrict__ out) {
    int n = blockIdx.x * 4 + (threadIdx.x >> 6);
    if (n >= NN) return;
    int lane = threadIdx.x & 63;
    int g = lane >> 3, ln = lane & 7;
    int row0 = rowptr[n];
    int d = rowptr[n + 1] - row0;
    float adn = ad2[n];

    float acc[8] = {};
    float wsum = 0.f;
    for (int j = 0; j <= d; j += 8) {
        int jj = j + g;
        int s = (jj < d) ? col[row0 + jj] : n;
        float e = lrelu(as2[s] + adn);
        float wgt = (jj <= d) ? __expf(e) : 0.f;
        wsum += wgt;
        float4 v0 = *(const float4*)&h2p[s * 64 + ln * 8];
        float4 v1 = *(const float4*)&h2p[s * 64 + ln * 8 + 4];
        acc[0] = fmaf(v0.x, wgt, acc[0]); acc[1] = fmaf(v0.y, wgt, acc[1]);
        acc[2] = fmaf(v0.z, wgt, acc[2]); acc[3] = fmaf(v0.w, wgt, acc[3]);
        acc[4] = fmaf(v1.x, wgt, acc[4]); acc[5] = fmaf(v1.y, wgt, acc[5]);
        acc[6] = fmaf(v1.z, wgt, acc[6]); acc[7] = fmaf(v1.w, wgt, acc[7]);
    }
    // reduce across groups; wsum is replicated 8x per group (one head) -> scale by 1/8
    #pragma unroll
    for (int off = 8; off <= 32; off <<= 1) {
        wsum += __shfl_xor(wsum, off, 64);
        #pragma unroll
        for (int k = 0; k < 8; ++k) acc[k] += __shfl_xor(acc[k], off, 64);
    }
    if (g == 0 && ln < 5) {   // channels ln*8..ln*8+7, only 0..39 valid
        float inv8 = 0.125f / (wsum * 0.125f + 1e-16f);
        float4 o0, o1;
        o0.x = fmaf(acc[0], inv8, b2[ln * 8 + 0]);
        o0.y = fmaf(acc[1], inv8, b2[ln * 8 + 1]);
        o0.z = fmaf(acc[2], inv8, b2[ln * 8 + 2]);
        o0.w = fmaf(acc[3], inv8, b2[ln * 8 + 3]);
        o1.x = fmaf(acc[4], inv8, b2[ln * 8 + 4]);
        o1.y = fmaf(acc[5], inv8, b2[ln * 8 + 5]);
        o1.z = fmaf(acc[6], inv8, b2[ln * 8 + 6]);
        o1.w = fmaf(acc[7], inv8, b2[ln * 8 + 7]);
        *(float4*)&out[n * NC + ln * 8] = o0;
        *(float4*)&out[n * NC + ln * 8 + 4] = o1;
    }
}

// ---------------- launcher ----------------

extern "C" void kernel_launch(void* const* d_in, const int* in_sizes, int n_in,
                              void* d_out, int out_size, void* d_ws, size_t ws_size,
                              hipStream_t stream) {
    const float* x = (const float*)d_in[0];
    const int* ei = (const int*)d_in[1];   // harness passes integer inputs as int32
    const int* src = ei;
    const int* dst = ei + NE;
    const float* W1 = (const float*)d_in[2];
    const float* asrc1 = (const float*)d_in[3];
    const float* adst1 = (const float*)d_in[4];
    const float* b1 = (const float*)d_in[5];
    const float* W2 = (const float*)d_in[6];
    const float* asrc2 = (const float*)d_in[7];
    const float* adst2 = (const float*)d_in[8];
    const float* b2 = (const float*)d_in[9];
    float* out = (float*)d_out;

    // workspace layout (total 46,801,152 B):
    //   [0,12800000)           h1b bf16 [N][64]
    //   [12800000,16000000)    as1 fp32 [N][8]
    //   [16000000,19200000)    ad1 fp32 [N][8]
    //   [0,25600000)           h2p fp32 [N][64]  (aliases h1b/as1/ad1 -- dead after agg1)
    //   [25600000,38400000)    h1outb bf16 [N][64]
    //   [38400000,38800000)    as2 fp32 [N]
    //   [38800000,39200000)    ad2 fp32 [N]
    //   [39200000,45600000)    col int [NE]
    //   [45600000,46000128)    rowptr int [N+1, padded]
    //   [46000128,46400128)    deg int [N]
    //   [46400128,46800128)    fill int [N]
    //   [46800128,46801152)    bsum/boff int [2*98, padded]
    char* ws = (char*)d_ws;
    unsigned short* h1b    = (unsigned short*)(ws + 0);
    float*          as1    = (float*)(ws + 12800000);
    float*          ad1    = (float*)(ws + 16000000);
    float*          h2p    = (float*)(ws + 0);
    unsigned short* h1outb = (unsigned short*)(ws + 25600000);
    float*          as2    = (float*)(ws + 38400000);
    float*          ad2    = (float*)(ws + 38800000);
    int*            col    = (int*)(ws + 39200000);
    int*            rowptr = (int*)(ws + 45600000);
    int*            deg    = (int*)(ws + 46000128);
    int*            fill   = (int*)(ws + 46400128);
    int*            bsum   = (int*)(ws + 46800128);
    int*            boff   = bsum + SCAN_B;

    zero_k<<<(2 * NN + 255) / 256, 256, 0, stream>>>(deg, 2 * NN);  // deg+fill contiguous

    hist_k<<<(NE + 255) / 256, 256, 0, stream>>>(dst, deg);
    scan1_k<<<SCAN_B, 256, 0, stream>>>(deg, rowptr, bsum);
    scan2_k<<<1, 128, 0, stream>>>(bsum, boff);
    scan3_k<<<SCAN_B, 256, 0, stream>>>(rowptr, boff);
    scatter_k<<<(NE + 255) / 256, 256, 0, stream>>>(src, dst, rowptr, fill, col);

    gemm1_k<<<(NN + 63) / 64, 256, 0, stream>>>(x, W1, h1b);
    attn1_k<<<(NN * NH + 255) / 256, 256, 0, stream>>>(h1b, asrc1, adst1, as1, ad1);
    agg1_k<<<(NN + 3) / 4, 256, 0, stream>>>(h1b, as1, ad1, rowptr, col, b1, h1outb);

    gemm2_k<<<(NN + 63) / 64, 256, 0, stream>>>(h1outb, W2, h2p);
    attn2_k<<<(NN + 255) / 256, 256, 0, stream>>>(h2p, asrc2, adst2, as2, ad2);
    agg2_k<<<(NN + 3) / 4, 256, 0, stream>>>(h2p, as2, ad2, rowptr, col, b2, out);
}

// Round 8
// 399.958 us; speedup vs baseline: 2.0902x; 1.0075x over previous
//
#include <hip/hip_runtime.h>
#include <hip/hip_bf16.h>

#define NN 100000
#define NE 1600000
#define NF 256
#define NC 40
#define NH 8
#define D1 64
#define NEG 0.2f
#define SCAN_B 98    // ceil(NN / 1024)
#define BSHIFT 7
#define BSZ 128
#define NB ((NN + BSZ - 1) / BSZ)   // 782 buckets
#define BPAD 32                      // bfill counter padding (ints) -> one 128B line each

static __device__ __forceinline__ float lrelu(float x) { return x > 0.f ? x : NEG * x; }

// unpack a uint holding 2 bf16 (little-endian: low half = first elem) -> 2 floats
static __device__ __forceinline__ float2 bfx2(unsigned u) {
    union { unsigned q; float f; } a, b;
    a.q = u << 16;
    b.q = u & 0xFFFF0000u;
    return make_float2(a.f, b.f);
}

// pack 2 floats -> uint of 2 bf16, RNE
static __device__ __forceinline__ unsigned packbf2(float x, float y) {
    unsigned xu = __float_as_uint(x), yu = __float_as_uint(y);
    xu = (xu + 0x7FFFu + ((xu >> 16) & 1u)) >> 16;
    yu = (yu + 0x7FFFu + ((yu >> 16) & 1u)) >> 16;
    return xu | (yu << 16);
}

// ---------------- zero deg+bfill (contiguous ints) ----------------

__global__ void zero_k(int* __restrict__ p, int n) {
    int i = blockIdx.x * blockDim.x + threadIdx.x;
    if (i < n) p[i] = 0;
}

// ---------------- CSR build ----------------

__global__ void hist_k(const int* __restrict__ dst, int* __restrict__ deg) {
    int i = blockIdx.x * blockDim.x + threadIdx.x;
    if (i < NE) atomicAdd(&deg[dst[i]], 1);
}

// device-wide scan, step 1: per-block scan of 1024 elements (256 thr x 4)
__launch_bounds__(256)
__global__ void scan1_k(const int* __restrict__ deg, int* __restrict__ rowptr, int* __restrict__ bsum) {
    __shared__ int ts[256];
    int b = blockIdx.x, t = threadIdx.x;
    int base = b * 1024 + t * 4;
    int v0 = 0, v1 = 0, v2 = 0, v3 = 0;
    if (base + 3 < NN) {
        int4 q = *(const int4*)&deg[base];
        v0 = q.x; v1 = q.y; v2 = q.z; v3 = q.w;
    } else {
        if (base < NN)     v0 = deg[base];
        if (base + 1 < NN) v1 = deg[base + 1];
        if (base + 2 < NN) v2 = deg[base + 2];
        if (base + 3 < NN) v3 = deg[base + 3];
    }
    int tot = v0 + v1 + v2 + v3;
    ts[t] = tot;
    __syncthreads();
    #pragma unroll
    for (int off = 1; off < 256; off <<= 1) {
        int x = (t >= off) ? ts[t - off] : 0;
        __syncthreads();
        ts[t] += x;
        __syncthreads();
    }
    int ex = ts[t] - tot;  // exclusive prefix within the block
    if (base < NN)     rowptr[base]     = ex;
    if (base + 1 < NN) rowptr[base + 1] = ex + v0;
    if (base + 2 < NN) rowptr[base + 2] = ex + v0 + v1;
    if (base + 3 < NN) rowptr[base + 3] = ex + v0 + v1 + v2;
    if (t == 255) bsum[b] = ts[255];
}

// step 2: scan the 98 block sums
__launch_bounds__(128)
__global__ void scan2_k(const int* __restrict__ bsum, int* __restrict__ boff) {
    __shared__ int s[128];
    int t = threadIdx.x;
    int v = (t < SCAN_B) ? bsum[t] : 0;
    s[t] = v;
    __syncthreads();
    #pragma unroll
    for (int off = 1; off < 128; off <<= 1) {
        int x = (t >= off) ? s[t - off] : 0;
        __syncthreads();
        s[t] += x;
        __syncthreads();
    }
    if (t < SCAN_B) boff[t] = s[t] - v;  // exclusive
}

// step 3: add block offsets; set rowptr[NN]
__launch_bounds__(256)
__global__ void scan3_k(int* __restrict__ rowptr, const int* __restrict__ boff) {
    int b = blockIdx.x, t = threadIdx.x;
    int off = boff[b];
    int base = b * 1024 + t * 4;
    if (base + 3 < NN) {
        int4* p = (int4*)&rowptr[base];
        int4 q = *p;
        q.x += off; q.y += off; q.z += off; q.w += off;
        *p = q;
    } else {
        #pragma unroll
        for (int k = 0; k < 4; ++k) if (base + k < NN) rowptr[base + k] += off;
    }
    if (b == 0 && t == 0) rowptr[NN] = NE;
}

// bucket pass: scatter packed (dst,src) into per-bucket streams.
// bucket b's region in tmp is exactly [rowptr[b*128], rowptr[(b+1)*128]) -- free from rowptr.
__global__ void bucket_k(const int* __restrict__ src, const int* __restrict__ dst,
                         const int* __restrict__ rowptr, int* __restrict__ bfill,
                         long long* __restrict__ tmp) {
    int i = blockIdx.x * blockDim.x + threadIdx.x;
    if (i < NE) {
        int d = dst[i];
        int b = d >> BSHIFT;
        int p = rowptr[b << BSHIFT] + atomicAdd(&bfill[b * BPAD], 1);
        tmp[p] = ((long long)d << 32) | (unsigned)src[i];
    }
}

// final pass: one block per bucket; LDS fill counters; col writes confined to ~8KB window.
__launch_bounds__(256)
__global__ void scatter2_k(const long long* __restrict__ tmp, const int* __restrict__ rowptr,
                           int* __restrict__ col) {
    __shared__ int lfill[BSZ];
    __shared__ int lrow[BSZ];
    int b = blockIdx.x;
    int n0 = b << BSHIFT;
    int t = threadIdx.x;
    if (t < BSZ) {
        lfill[t] = 0;
        if (n0 + t < NN) lrow[t] = rowptr[n0 + t];
    }
    __syncthreads();
    int hi = n0 + BSZ; if (hi > NN) hi = NN;
    int beg = rowptr[n0];
    int end = rowptr[hi];
    for (int p = beg + t; p < end; p += 256) {
        long long v = tmp[p];
        int s = (int)(v & 0xFFFFFFFFLL);
        int d = (int)(v >> 32);
        int o = atomicAdd(&lfill[d - n0], 1);
        col[lrow[d - n0] + o] = s;
    }
}

// ---------------- GEMM1: h1 = x @ W1  [100000,256]x[256,64] -> bf16 ----------------
// x staged in LDS as bf16 (25.1KB total LDS -> 6 blocks/CU), float4 staging loads.

__launch_bounds__(256)
__global__ void gemm1_k(const float* __restrict__ x, const float* __restrict__ W,
                        unsigned short* __restrict__ h1b) {
    __shared__ unsigned short xs[64 * 68];   // bf16 [row][k], stride 68
    __shared__ float ws[64 * 64];            // fp32 [k][col]
    int r0 = blockIdx.x * 64;
    int tid = threadIdx.x;
    int tr = tid >> 4, tc = tid & 15;
    float acc[4][4] = {};
    for (int kt = 0; kt < 4; ++kt) {
        #pragma unroll
        for (int it = 0; it < 4; ++it) {
            int idx = tid + it * 256;       // 0..1023
            int row = idx >> 4;             // 0..63
            int kb = (idx & 15) * 4;
            int gr = r0 + row;
            float4 v = (gr < NN) ? *(const float4*)&x[gr * NF + kt * 64 + kb]
                                 : make_float4(0.f, 0.f, 0.f, 0.f);
            uint2 pk;
            pk.x = packbf2(v.x, v.y);
            pk.y = packbf2(v.z, v.w);
            *(uint2*)&xs[row * 68 + kb] = pk;
        }
        #pragma unroll
        for (int it = 0; it < 4; ++it) {
            int idx = tid + it * 256;
            int k = idx >> 4;
            int cb = (idx & 15) * 4;
            *(float4*)&ws[k * 64 + cb] = *(const float4*)&W[(kt * 64 + k) * 64 + cb];
        }
        __syncthreads();
        #pragma unroll 4
        for (int k = 0; k < 64; k += 2) {
            float a0[4], a1[4];
            #pragma unroll
            for (int j = 0; j < 4; ++j) {
                unsigned u = *(const unsigned*)&xs[(tr * 4 + j) * 68 + k];
                float2 p = bfx2(u);
                a0[j] = p.x; a1[j] = p.y;
            }
            float4 bv0 = *(const float4*)&ws[k * 64 + tc * 4];
            float4 bv1 = *(const float4*)&ws[(k + 1) * 64 + tc * 4];
            float b0[4] = {bv0.x, bv0.y, bv0.z, bv0.w};
            float b1[4] = {bv1.x, bv1.y, bv1.z, bv1.w};
            #pragma unroll
            for (int j = 0; j < 4; ++j)
                #pragma unroll
                for (int i = 0; i < 4; ++i)
                    acc[j][i] = fmaf(a1[j], b1[i], fmaf(a0[j], b0[i], acc[j][i]));
        }
        __syncthreads();
    }
    #pragma unroll
    for (int j = 0; j < 4; ++j) {
        int gr = r0 + tr * 4 + j;
        if (gr < NN) {
            uint2 v;
            v.x = packbf2(acc[j][0], acc[j][1]);
            v.y = packbf2(acc[j][2], acc[j][3]);
            *(uint2*)&h1b[gr * D1 + tc * 4] = v;
        }
    }
}

// ---------------- attention coefficients layer 1 ----------------

__global__ void attn1_k(const unsigned short* __restrict__ h1b, const float* __restrict__ asrc,
                        const float* __restrict__ adst,
                        float* __restrict__ as1, float* __restrict__ ad1) {
    int t = blockIdx.x * blockDim.x + threadIdx.x;
    if (t >= NN * NH) return;
    int n = t >> 3, h = t & 7;
    uint4 v = *(const uint4*)&h1b[n * D1 + h * 8];
    float hv[8];
    float2 p;
    p = bfx2(v.x); hv[0] = p.x; hv[1] = p.y;
    p = bfx2(v.y); hv[2] = p.x; hv[3] = p.y;
    p = bfx2(v.z); hv[4] = p.x; hv[5] = p.y;
    p = bfx2(v.w); hv[6] = p.x; hv[7] = p.y;
    float sa = 0.f, sd = 0.f;
    #pragma unroll
    for (int c = 0; c < 8; ++c) {
        sa = fmaf(hv[c], asrc[h * 8 + c], sa);
        sd = fmaf(hv[c], adst[h * 8 + c], sd);
    }
    as1[t] = sa;
    ad1[t] = sd;
}

// ---------------- aggregation layer 1: single fused pass, 8 edges in flight ----------------

__launch_bounds__(256)
__global__ void agg1_k(const unsigned short* __restrict__ h1b, const float* __restrict__ as1,
                       const float* __restrict__ ad1,
                       const int* __restrict__ rowptr, const int* __restrict__ col,
                       const float* __restrict__ b1, unsigned short* __restrict__ h1outb) {
    int n = blockIdx.x * 4 + (threadIdx.x >> 6);
    if (n >= NN) return;
    int lane = threadIdx.x & 63;
    int g = lane >> 3, ln = lane & 7;
    int row0 = rowptr[n];
    int d = rowptr[n + 1] - row0;
    float adh = ad1[n * 8 + ln];

    float acc[8] = {};
    float wsum = 0.f;
    for (int j = 0; j <= d; j += 8) {
        int jj = j + g;
        int s = (jj < d) ? col[row0 + jj] : n;   // virtual self-loop at jj==d
        float e = lrelu(as1[s * 8 + ln] + adh);
        float wgt = (jj <= d) ? __expf(e) : 0.f;
        wsum += wgt;
        uint4 hv = *(const uint4*)&h1b[s * D1 + ln * 8];
        float2 p;
        p = bfx2(hv.x); acc[0] = fmaf(p.x, wgt, acc[0]); acc[1] = fmaf(p.y, wgt, acc[1]);
        p = bfx2(hv.y); acc[2] = fmaf(p.x, wgt, acc[2]); acc[3] = fmaf(p.y, wgt, acc[3]);
        p = bfx2(hv.z); acc[4] = fmaf(p.x, wgt, acc[4]); acc[5] = fmaf(p.y, wgt, acc[5]);
        p = bfx2(hv.w); acc[6] = fmaf(p.x, wgt, acc[6]); acc[7] = fmaf(p.y, wgt, acc[7]);
    }
    #pragma unroll
    for (int off = 8; off <= 32; off <<= 1) {
        wsum += __shfl_xor(wsum, off, 64);
        #pragma unroll
        for (int k = 0; k < 8; ++k) acc[k] += __shfl_xor(acc[k], off, 64);
    }
    if (g == 0) {
        float inv = 1.f / (wsum + 1e-16f);
        unsigned u[4];
        #pragma unroll
        for (int k = 0; k < 4; ++k) {
            float v0 = fmaf(acc[2 * k], inv, b1[ln * 8 + 2 * k]);
            float v1 = fmaf(acc[2 * k + 1], inv, b1[ln * 8 + 2 * k + 1]);
            v0 = (v0 > 0.f) ? v0 : (__expf(v0) - 1.f);   // ELU
            v1 = (v1 > 0.f) ? v1 : (__expf(v1) - 1.f);
            u[k] = packbf2(v0, v1);
        }
        uint4 w = {u[0], u[1], u[2], u[3]};
        *(uint4*)&h1outb[n * D1 + ln * 8] = w;
    }
}

// ---------------- GEMM2: h2p = h1out @ W2, padded [N][64] (cols 40..63 = 0) ----------------

__launch_bounds__(256)
__global__ void gemm2_k(const unsigned short* __restrict__ h1outb, const float* __restrict__ W2,
                        float* __restrict__ h2p) {
    __shared__ float xs[64 * 68];
    __shared__ float ws[64 * 40];
    int r0 = blockIdx.x * 64;
    int tid = threadIdx.x;
    #pragma unroll
    for (int it = 0; it < 4; ++it) {
        int idx = tid + it * 256;       // 0..1023
        int row = idx >> 4;             // 0..63
        int q = (idx & 15) * 4;         // col quad base
        int gr = r0 + row;
        float f0 = 0.f, f1 = 0.f, f2 = 0.f, f3 = 0.f;
        if (gr < NN) {
            uint2 v = *(const uint2*)&h1outb[gr * D1 + q];
            float2 p0 = bfx2(v.x), p1 = bfx2(v.y);
            f0 = p0.x; f1 = p0.y; f2 = p1.x; f3 = p1.y;
        }
        xs[row * 68 + q] = f0;
        xs[row * 68 + q + 1] = f1;
        xs[row * 68 + q + 2] = f2;
        xs[row * 68 + q + 3] = f3;
    }
    #pragma unroll
    for (int it = 0; it < 10; ++it) {
        int idx = tid + it * 256;
        if (idx < 64 * 40) ws[idx] = W2[idx];
    }
    __syncthreads();
    int r = tid >> 2, q = tid & 3;
    float acc[10] = {};
    #pragma unroll 4
    for (int k = 0; k < 64; ++k) {
        float xv = xs[r * 68 + k];
        #pragma unroll
        for (int i = 0; i < 10; ++i)
            acc[i] = fmaf(xv, ws[k * 40 + q * 10 + i], acc[i]);
    }
    int gr = r0 + r;
    if (gr < NN) {
        #pragma unroll
        for (int i = 0; i < 10; ++i) h2p[gr * 64 + q * 10 + i] = acc[i];
    }
    // zero pad columns 40..63
    for (int idx = tid; idx < 64 * 24; idx += 256) {
        int row = idx / 24, c = 40 + idx % 24;
        int g2 = r0 + row;
        if (g2 < NN) h2p[g2 * 64 + c] = 0.f;
    }
}

// ---------------- attention coefficients layer 2 ----------------

__global__ void attn2_k(const float* __restrict__ h2p, const float* __restrict__ asrc,
                        const float* __restrict__ adst,
                        float* __restrict__ as2, float* __restrict__ ad2) {
    int n = blockIdx.x * blockDim.x + threadIdx.x;
    if (n >= NN) return;
    float sa = 0.f, sd = 0.f;
    #pragma unroll
    for (int c0 = 0; c0 < NC; c0 += 4) {
        float4 v = *(const float4*)&h2p[n * 64 + c0];
        float4 a = *(const float4*)&asrc[c0];
        float4 b = *(const float4*)&adst[c0];
        sa += v.x * a.x + v.y * a.y + v.z * a.z + v.w * a.w;
        sd += v.x * b.x + v.y * b.y + v.z * b.z + v.w * b.w;
    }
    as2[n] = sa;
    ad2[n] = sd;
}

// ---------------- aggregation layer 2: fused single pass, 8 edges in flight ----------------

__launch_bounds__(256)
__global__ void agg2_k(const float* __restrict__ h2p, const float* __restrict__ as2,
                       const float* __restrict__ ad2,
                       const int* __restrict__ rowptr, const int* __restrict__ col,
                       const float* __restrict__ b2, float* __restrict__ out) {
    int n = blockIdx.x * 4 + (threadIdx.x >> 6);
    if (n >= NN) return;
    int lane = threadIdx.x & 63;
    int g = lane >> 3, ln = lane & 7;
    int row0 = rowptr[n];
    int d = rowptr[n + 1] - row0;
    float adn = ad2[n];

    float acc[8] = {};
    float wsum = 0.f;
    for (int j = 0; j <= d; j += 8) {
        int jj = j + g;
        int s = (jj < d) ? col[row0 + jj] : n;
        float e = lrelu(as2[s] + adn);
        float wgt = (jj <= d) ? __expf(e) : 0.f;
        wsum += wgt;
        float4 v0 = *(const float4*)&h2p[s * 64 + ln * 8];
        float4 v1 = *(const float4*)&h2p[s * 64 + ln * 8 + 4];
        acc[0] = fmaf(v0.x, wgt, acc[0]); acc[1] = fmaf(v0.y, wgt, acc[1]);
        acc[2] = fmaf(v0.z, wgt, acc[2]); acc[3] = fmaf(v0.w, wgt, acc[3]);
        acc[4] = fmaf(v1.x, wgt, acc[4]); acc[5] = fmaf(v1.y, wgt, acc[5]);
        acc[6] = fmaf(v1.z, wgt, acc[6]); acc[7] = fmaf(v1.w, wgt, acc[7]);
    }
    // reduce across groups; wsum is replicated 8x per group (one head) -> scale by 1/8
    #pragma unroll
    for (int off = 8; off <= 32; off <<= 1) {
        wsum += __shfl_xor(wsum, off, 64);
        #pragma unroll
        for (int k = 0; k < 8; ++k) acc[k] += __shfl_xor(acc[k], off, 64);
    }
    if (g == 0 && ln < 5) {   // channels ln*8..ln*8+7, only 0..39 valid
        float inv8 = 0.125f / (wsum * 0.125f + 1e-16f);
        float4 o0, o1;
        o0.x = fmaf(acc[0], inv8, b2[ln * 8 + 0]);
        o0.y = fmaf(acc[1], inv8, b2[ln * 8 + 1]);
        o0.z = fmaf(acc[2], inv8, b2[ln * 8 + 2]);
        o0.w = fmaf(acc[3], inv8, b2[ln * 8 + 3]);
        o1.x = fmaf(acc[4], inv8, b2[ln * 8 + 4]);
        o1.y = fmaf(acc[5], inv8, b2[ln * 8 + 5]);
        o1.z = fmaf(acc[6], inv8, b2[ln * 8 + 6]);
        o1.w = fmaf(acc[7], inv8, b2[ln * 8 + 7]);
        *(float4*)&out[n * NC + ln * 8] = o0;
        *(float4*)&out[n * NC + ln * 8 + 4] = o1;
    }
}

// ---------------- launcher ----------------

extern "C" void kernel_launch(void* const* d_in, const int* in_sizes, int n_in,
                              void* d_out, int out_size, void* d_ws, size_t ws_size,
                              hipStream_t stream) {
    const float* x = (const float*)d_in[0];
    const int* ei = (const int*)d_in[1];   // harness passes integer inputs as int32
    const int* src = ei;
    const int* dst = ei + NE;
    const float* W1 = (const float*)d_in[2];
    const float* asrc1 = (const float*)d_in[3];
    const float* adst1 = (const float*)d_in[4];
    const float* b1 = (const float*)d_in[5];
    const float* W2 = (const float*)d_in[6];
    const float* asrc2 = (const float*)d_in[7];
    const float* adst2 = (const float*)d_in[8];
    const float* b2 = (const float*)d_in[9];
    float* out = (float*)d_out;

    // workspace layout (total ~46.6 MB):
    //   [0,12800000)           h1b bf16 [N][64]
    //   [12800000,16000000)    as1 fp32 [N][8]
    //   [16000000,19200000)    ad1 fp32 [N][8]
    //   [0,25600000)           h2p fp32 [N][64]   (aliases h1b/as1/ad1 -- dead after agg1)
    //   [25600000,38400000)    h1outb bf16 [N][64]; tmp long long [NE] aliases (dead after scatter2)
    //   [38400000,38800000)    as2 fp32 [N]
    //   [38800000,39200000)    ad2 fp32 [N]
    //   [39200000,45600000)    col int [NE]
    //   [45600000,46000128)    rowptr int [N+1, padded]
    //   [46000128,46400128)    deg int [N]
    //   [46400128,46500224)    bfill int [NB*32]
    //   [46500224,46501008)    bsum/boff int [2*98]
    char* ws = (char*)d_ws;
    unsigned short* h1b    = (unsigned short*)(ws + 0);
    float*          as1    = (float*)(ws + 12800000);
    float*          ad1    = (float*)(ws + 16000000);
    float*          h2p    = (float*)(ws + 0);
    unsigned short* h1outb = (unsigned short*)(ws + 25600000);
    long long*      tmp    = (long long*)(ws + 25600000);   // alias: dead before agg1 writes h1outb
    float*          as2    = (float*)(ws + 38400000);
    float*          ad2    = (float*)(ws + 38800000);
    int*            col    = (int*)(ws + 39200000);
    int*            rowptr = (int*)(ws + 45600000);
    int*            deg    = (int*)(ws + 46000128);
    int*            bfill  = (int*)(ws + 46400128);
    int*            bsum   = (int*)(ws + 46500224);
    int*            boff   = bsum + SCAN_B;

    // zero deg + bfill (contiguous: 100000 + 782*32 = 125024 ints)
    zero_k<<<(NN + NB * BPAD + 255) / 256, 256, 0, stream>>>(deg, NN + NB * BPAD);

    hist_k<<<(NE + 255) / 256, 256, 0, stream>>>(dst, deg);
    scan1_k<<<SCAN_B, 256, 0, stream>>>(deg, rowptr, bsum);
    scan2_k<<<1, 128, 0, stream>>>(bsum, boff);
    scan3_k<<<SCAN_B, 256, 0, stream>>>(rowptr, boff);
    bucket_k<<<(NE + 255) / 256, 256, 0, stream>>>(src, dst, rowptr, bfill, tmp);
    scatter2_k<<<NB, 256, 0, stream>>>(tmp, rowptr, col);

    gemm1_k<<<(NN + 63) / 64, 256, 0, stream>>>(x, W1, h1b);
    attn1_k<<<(NN * NH + 255) / 256, 256, 0, stream>>>(h1b, asrc1, adst1, as1, ad1);
    agg1_k<<<(NN + 3) / 4, 256, 0, stream>>>(h1b, as1, ad1, rowptr, col, b1, h1outb);

    gemm2_k<<<(NN + 63) / 64, 256, 0, stream>>>(h1outb, W2, h2p);
    attn2_k<<<(NN + 255) / 256, 256, 0, stream>>>(h2p, asrc2, adst2, as2, ad2);
    agg2_k<<<(NN + 3) / 4, 256, 0, stream>>>(h2p, as2, ad2, rowptr, col, b2, out);
}

// Round 9
// 264.959 us; speedup vs baseline: 3.1552x; 1.5095x over previous
//
#include <hip/hip_runtime.h>
#include <hip/hip_bf16.h>

#define NN 100000
#define NE 1600000
#define NF 256
#define NC 40
#define NH 8
#define D1 64
#define NEG 0.2f
#define BSHIFT 7
#define BSZ 128
#define NB ((NN + BSZ - 1) / BSZ)     // 782 buckets of 128 nodes
#define EPB 4096
#define NBLK ((NE + EPB - 1) / EPB)   // 391 edge blocks

static __device__ __forceinline__ float lrelu(float x) { return x > 0.f ? x : NEG * x; }

// unpack a uint holding 2 bf16 -> 2 floats
static __device__ __forceinline__ float2 bfx2(unsigned u) {
    union { unsigned q; float f; } a, b;
    a.q = u << 16;
    b.q = u & 0xFFFF0000u;
    return make_float2(a.f, b.f);
}

// pack 2 floats -> uint of 2 bf16, RNE
static __device__ __forceinline__ unsigned packbf2(float x, float y) {
    unsigned xu = __float_as_uint(x), yu = __float_as_uint(y);
    xu = (xu + 0x7FFFu + ((xu >> 16) & 1u)) >> 16;
    yu = (yu + 0x7FFFu + ((yu >> 16) & 1u)) >> 16;
    return xu | (yu << 16);
}

// ---------------- CSR build: deterministic multi-split (no global atomics) ----------------

// pass 1: per-edge-block bucket histogram -> cnt[i][b]
__launch_bounds__(256)
__global__ void bhist_k(const int* __restrict__ dst, int* __restrict__ cnt) {
    __shared__ int hist[NB];
    int i = blockIdx.x, t = threadIdx.x;
    for (int b = t; b < NB; b += 256) hist[b] = 0;
    __syncthreads();
    int e0 = i * EPB;
    #pragma unroll
    for (int k = 0; k < EPB / 256; ++k) {
        int e = e0 + k * 256 + t;
        if (e < NE) atomicAdd(&hist[dst[e] >> BSHIFT], 1);
    }
    __syncthreads();
    for (int b = t; b < NB; b += 256) cnt[i * NB + b] = hist[b];
}

// pass 2: per bucket b, exclusive scan of cnt[*][b] over blocks (in place) + total
__launch_bounds__(256)
__global__ void bscan2_k(int* __restrict__ cnt, int* __restrict__ btot) {
    __shared__ int ps[256];
    int b = blockIdx.x, t = threadIdx.x;
    int i0 = 2 * t;
    int a = (i0 < NBLK) ? cnt[i0 * NB + b] : 0;
    int c = (i0 + 1 < NBLK) ? cnt[(i0 + 1) * NB + b] : 0;
    int s = a + c;
    ps[t] = s;
    __syncthreads();
    #pragma unroll
    for (int off = 1; off < 256; off <<= 1) {
        int x = (t >= off) ? ps[t - off] : 0;
        __syncthreads();
        ps[t] += x;
        __syncthreads();
    }
    int ex = ps[t] - s;
    if (i0 < NBLK) cnt[i0 * NB + b] = ex;
    if (i0 + 1 < NBLK) cnt[(i0 + 1) * NB + b] = ex + a;
    if (t == 255) btot[b] = ps[255];
}

// pass 3: exclusive scan of the 782 bucket totals -> bbase (bbase[NB] = NE)
__launch_bounds__(256)
__global__ void bscanB_k(const int* __restrict__ btot, int* __restrict__ bbase) {
    __shared__ int ps[256];
    int t = threadIdx.x;
    int j0 = 4 * t;
    int v[4]; int s = 0;
    #pragma unroll
    for (int k = 0; k < 4; ++k) { v[k] = (j0 + k < NB) ? btot[j0 + k] : 0; s += v[k]; }
    ps[t] = s;
    __syncthreads();
    #pragma unroll
    for (int off = 1; off < 256; off <<= 1) {
        int x = (t >= off) ? ps[t - off] : 0;
        __syncthreads();
        ps[t] += x;
        __syncthreads();
    }
    int run = ps[t] - s;
    #pragma unroll
    for (int k = 0; k < 4; ++k) { if (j0 + k < NB) bbase[j0 + k] = run; run += v[k]; }
    if (t == 0) bbase[NB] = NE;
}

// pass 4: place records into block-private contiguous sub-ranges (LDS counters only)
__launch_bounds__(256)
__global__ void bplace_k(const int* __restrict__ src, const int* __restrict__ dst,
                         const int* __restrict__ cnt, const int* __restrict__ bbase,
                         long long* __restrict__ tmp) {
    __shared__ int loff[NB];
    int i = blockIdx.x, t = threadIdx.x;
    for (int b = t; b < NB; b += 256) loff[b] = bbase[b] + cnt[i * NB + b];
    __syncthreads();
    int e0 = i * EPB;
    #pragma unroll
    for (int k = 0; k < EPB / 256; ++k) {
        int e = e0 + k * 256 + t;
        if (e < NE) {
            int d = dst[e];
            int p = atomicAdd(&loff[d >> BSHIFT], 1);
            tmp[p] = ((long long)d << 32) | (unsigned)src[e];
        }
    }
}

// pass 5: per bucket, count per node -> rowptr, then place col within 8KB window
__launch_bounds__(256)
__global__ void scatter2_k(const long long* __restrict__ tmp, const int* __restrict__ bbase,
                           int* __restrict__ rowptr, int* __restrict__ col) {
    __shared__ int lcnt[BSZ];
    __shared__ int lrow[BSZ];
    __shared__ int ls[BSZ];
    int b = blockIdx.x, t = threadIdx.x;
    int n0 = b << BSHIFT;
    if (t < BSZ) lcnt[t] = 0;
    __syncthreads();
    int beg = bbase[b], end = bbase[b + 1];
    for (int p = beg + t; p < end; p += 256) {
        int d = (int)(tmp[p] >> 32);
        atomicAdd(&lcnt[d - n0], 1);
    }
    __syncthreads();
    if (t < BSZ) ls[t] = lcnt[t];
    __syncthreads();
    #pragma unroll
    for (int off = 1; off < BSZ; off <<= 1) {
        int x = 0;
        if (t < BSZ && t >= off) x = ls[t - off];
        __syncthreads();
        if (t < BSZ) ls[t] += x;
        __syncthreads();
    }
    if (t < BSZ) {
        int ex = ls[t] - lcnt[t];
        lrow[t] = beg + ex;
        if (n0 + t < NN) rowptr[n0 + t] = beg + ex;
        lcnt[t] = 0;
    }
    if (b == NB - 1 && t == 0) rowptr[NN] = NE;
    __syncthreads();
    for (int p = beg + t; p < end; p += 256) {
        long long v = tmp[p];
        int d = (int)(v >> 32);
        int s = (int)(v & 0xFFFFFFFFLL);
        int o = atomicAdd(&lcnt[d - n0], 1);
        col[lrow[d - n0] + o] = s;
    }
}

// ---------------- GEMM1: h1 = x @ W1  [100000,256]x[256,64] -> bf16 ----------------

__launch_bounds__(256)
__global__ void gemm1_k(const float* __restrict__ x, const float* __restrict__ W,
                        unsigned short* __restrict__ h1b) {
    __shared__ unsigned short xs[64 * 68];   // bf16 [row][k], stride 68
    __shared__ float ws[64 * 64];            // fp32 [k][col]
    int r0 = blockIdx.x * 64;
    int tid = threadIdx.x;
    int tr = tid >> 4, tc = tid & 15;
    float acc[4][4] = {};
    for (int kt = 0; kt < 4; ++kt) {
        #pragma unroll
        for (int it = 0; it < 4; ++it) {
            int idx = tid + it * 256;       // 0..1023
            int row = idx >> 4;             // 0..63
            int kb = (idx & 15) * 4;
            int gr = r0 + row;
            float4 v = (gr < NN) ? *(const float4*)&x[gr * NF + kt * 64 + kb]
                                 : make_float4(0.f, 0.f, 0.f, 0.f);
            uint2 pk;
            pk.x = packbf2(v.x, v.y);
            pk.y = packbf2(v.z, v.w);
            *(uint2*)&xs[row * 68 + kb] = pk;
        }
        #pragma unroll
        for (int it = 0; it < 4; ++it) {
            int idx = tid + it * 256;
            int k = idx >> 4;
            int cb = (idx & 15) * 4;
            *(float4*)&ws[k * 64 + cb] = *(const float4*)&W[(kt * 64 + k) * 64 + cb];
        }
        __syncthreads();
        #pragma unroll 4
        for (int k = 0; k < 64; k += 2) {
            float a0[4], a1[4];
            #pragma unroll
            for (int j = 0; j < 4; ++j) {
                unsigned u = *(const unsigned*)&xs[(tr * 4 + j) * 68 + k];
                float2 p = bfx2(u);
                a0[j] = p.x; a1[j] = p.y;
            }
            float4 bv0 = *(const float4*)&ws[k * 64 + tc * 4];
            float4 bv1 = *(const float4*)&ws[(k + 1) * 64 + tc * 4];
            float b0[4] = {bv0.x, bv0.y, bv0.z, bv0.w};
            float b1[4] = {bv1.x, bv1.y, bv1.z, bv1.w};
            #pragma unroll
            for (int j = 0; j < 4; ++j)
                #pragma unroll
                for (int i = 0; i < 4; ++i)
                    acc[j][i] = fmaf(a1[j], b1[i], fmaf(a0[j], b0[i], acc[j][i]));
        }
        __syncthreads();
    }
    #pragma unroll
    for (int j = 0; j < 4; ++j) {
        int gr = r0 + tr * 4 + j;
        if (gr < NN) {
            uint2 v;
            v.x = packbf2(acc[j][0], acc[j][1]);
            v.y = packbf2(acc[j][2], acc[j][3]);
            *(uint2*)&h1b[gr * D1 + tc * 4] = v;
        }
    }
}

// ---------------- attention coefficients layer 1 ----------------

__global__ void attn1_k(const unsigned short* __restrict__ h1b, const float* __restrict__ asrc,
                        const float* __restrict__ adst,
                        float* __restrict__ as1, float* __restrict__ ad1) {
    int t = blockIdx.x * blockDim.x + threadIdx.x;
    if (t >= NN * NH) return;
    int n = t >> 3, h = t & 7;
    uint4 v = *(const uint4*)&h1b[n * D1 + h * 8];
    float hv[8];
    float2 p;
    p = bfx2(v.x); hv[0] = p.x; hv[1] = p.y;
    p = bfx2(v.y); hv[2] = p.x; hv[3] = p.y;
    p = bfx2(v.z); hv[4] = p.x; hv[5] = p.y;
    p = bfx2(v.w); hv[6] = p.x; hv[7] = p.y;
    float sa = 0.f, sd = 0.f;
    #pragma unroll
    for (int c = 0; c < 8; ++c) {
        sa = fmaf(hv[c], asrc[h * 8 + c], sa);
        sd = fmaf(hv[c], adst[h * 8 + c], sd);
    }
    as1[t] = sa;
    ad1[t] = sd;
}

// ---------------- aggregation layer 1: single fused pass, 8 edges in flight ----------------

__launch_bounds__(256)
__global__ void agg1_k(const unsigned short* __restrict__ h1b, const float* __restrict__ as1,
                       const float* __restrict__ ad1,
                       const int* __restrict__ rowptr, const int* __restrict__ col,
                       const float* __restrict__ b1, unsigned short* __restrict__ h1outb) {
    int n = blockIdx.x * 4 + (threadIdx.x >> 6);
    if (n >= NN) return;
    int lane = threadIdx.x & 63;
    int g = lane >> 3, ln = lane & 7;
    int row0 = rowptr[n];
    int d = rowptr[n + 1] - row0;
    float adh = ad1[n * 8 + ln];

    float acc[8] = {};
    float wsum = 0.f;
    for (int j = 0; j <= d; j += 8) {
        int jj = j + g;
        int s = (jj < d) ? col[row0 + jj] : n;   // virtual self-loop at jj==d
        float e = lrelu(as1[s * 8 + ln] + adh);
        float wgt = (jj <= d) ? __expf(e) : 0.f;
        wsum += wgt;
        uint4 hv = *(const uint4*)&h1b[s * D1 + ln * 8];
        float2 p;
        p = bfx2(hv.x); acc[0] = fmaf(p.x, wgt, acc[0]); acc[1] = fmaf(p.y, wgt, acc[1]);
        p = bfx2(hv.y); acc[2] = fmaf(p.x, wgt, acc[2]); acc[3] = fmaf(p.y, wgt, acc[3]);
        p = bfx2(hv.z); acc[4] = fmaf(p.x, wgt, acc[4]); acc[5] = fmaf(p.y, wgt, acc[5]);
        p = bfx2(hv.w); acc[6] = fmaf(p.x, wgt, acc[6]); acc[7] = fmaf(p.y, wgt, acc[7]);
    }
    #pragma unroll
    for (int off = 8; off <= 32; off <<= 1) {
        wsum += __shfl_xor(wsum, off, 64);
        #pragma unroll
        for (int k = 0; k < 8; ++k) acc[k] += __shfl_xor(acc[k], off, 64);
    }
    if (g == 0) {
        float inv = 1.f / (wsum + 1e-16f);
        unsigned u[4];
        #pragma unroll
        for (int k = 0; k < 4; ++k) {
            float v0 = fmaf(acc[2 * k], inv, b1[ln * 8 + 2 * k]);
            float v1 = fmaf(acc[2 * k + 1], inv, b1[ln * 8 + 2 * k + 1]);
            v0 = (v0 > 0.f) ? v0 : (__expf(v0) - 1.f);   // ELU
            v1 = (v1 > 0.f) ? v1 : (__expf(v1) - 1.f);
            u[k] = packbf2(v0, v1);
        }
        uint4 w = {u[0], u[1], u[2], u[3]};
        *(uint4*)&h1outb[n * D1 + ln * 8] = w;
    }
}

// ---------------- GEMM2: h2p = h1out @ W2, padded [N][64] (cols 40..63 = 0) ----------------

__launch_bounds__(256)
__global__ void gemm2_k(const unsigned short* __restrict__ h1outb, const float* __restrict__ W2,
                        float* __restrict__ h2p) {
    __shared__ float xs[64 * 68];
    __shared__ float ws[64 * 40];
    int r0 = blockIdx.x * 64;
    int tid = threadIdx.x;
    #pragma unroll
    for (int it = 0; it < 4; ++it) {
        int idx = tid + it * 256;       // 0..1023
        int row = idx >> 4;             // 0..63
        int q = (idx & 15) * 4;         // col quad base
        int gr = r0 + row;
        float f0 = 0.f, f1 = 0.f, f2 = 0.f, f3 = 0.f;
        if (gr < NN) {
            uint2 v = *(const uint2*)&h1outb[gr * D1 + q];
            float2 p0 = bfx2(v.x), p1 = bfx2(v.y);
            f0 = p0.x; f1 = p0.y; f2 = p1.x; f3 = p1.y;
        }
        xs[row * 68 + q] = f0;
        xs[row * 68 + q + 1] = f1;
        xs[row * 68 + q + 2] = f2;
        xs[row * 68 + q + 3] = f3;
    }
    #pragma unroll
    for (int it = 0; it < 10; ++it) {
        int idx = tid + it * 256;
        if (idx < 64 * 40) ws[idx] = W2[idx];
    }
    __syncthreads();
    int r = tid >> 2, q = tid & 3;
    float acc[10] = {};
    #pragma unroll 4
    for (int k = 0; k < 64; ++k) {
        float xv = xs[r * 68 + k];
        #pragma unroll
        for (int i = 0; i < 10; ++i)
            acc[i] = fmaf(xv, ws[k * 40 + q * 10 + i], acc[i]);
    }
    int gr = r0 + r;
    if (gr < NN) {
        #pragma unroll
        for (int i = 0; i < 10; ++i) h2p[gr * 64 + q * 10 + i] = acc[i];
    }
    // zero pad columns 40..63
    for (int idx = tid; idx < 64 * 24; idx += 256) {
        int row = idx / 24, c = 40 + idx % 24;
        int g2 = r0 + row;
        if (g2 < NN) h2p[g2 * 64 + c] = 0.f;
    }
}

// ---------------- attention coefficients layer 2 ----------------

__global__ void attn2_k(const float* __restrict__ h2p, const float* __restrict__ asrc,
                        const float* __restrict__ adst,
                        float* __restrict__ as2, float* __restrict__ ad2) {
    int n = blockIdx.x * blockDim.x + threadIdx.x;
    if (n >= NN) return;
    float sa = 0.f, sd = 0.f;
    #pragma unroll
    for (int c0 = 0; c0 < NC; c0 += 4) {
        float4 v = *(const float4*)&h2p[n * 64 + c0];
        float4 a = *(const float4*)&asrc[c0];
        float4 b = *(const float4*)&adst[c0];
        sa += v.x * a.x + v.y * a.y + v.z * a.z + v.w * a.w;
        sd += v.x * b.x + v.y * b.y + v.z * b.z + v.w * b.w;
    }
    as2[n] = sa;
    ad2[n] = sd;
}

// ---------------- aggregation layer 2: fused single pass, 8 edges in flight ----------------

__launch_bounds__(256)
__global__ void agg2_k(const float* __restrict__ h2p, const float* __restrict__ as2,
                       const float* __restrict__ ad2,
                       const int* __restrict__ rowptr, const int* __restrict__ col,
                       const float* __restrict__ b2, float* __restrict__ out) {
    int n = blockIdx.x * 4 + (threadIdx.x >> 6);
    if (n >= NN) return;
    int lane = threadIdx.x & 63;
    int g = lane >> 3, ln = lane & 7;
    int row0 = rowptr[n];
    int d = rowptr[n + 1] - row0;
    float adn = ad2[n];

    float acc[8] = {};
    float wsum = 0.f;
    for (int j = 0; j <= d; j += 8) {
        int jj = j + g;
        int s = (jj < d) ? col[row0 + jj] : n;
        float e = lrelu(as2[s] + adn);
        float wgt = (jj <= d) ? __expf(e) : 0.f;
        wsum += wgt;
        float4 v0 = *(const float4*)&h2p[s * 64 + ln * 8];
        float4 v1 = *(const float4*)&h2p[s * 64 + ln * 8 + 4];
        acc[0] = fmaf(v0.x, wgt, acc[0]); acc[1] = fmaf(v0.y, wgt, acc[1]);
        acc[2] = fmaf(v0.z, wgt, acc[2]); acc[3] = fmaf(v0.w, wgt, acc[3]);
        acc[4] = fmaf(v1.x, wgt, acc[4]); acc[5] = fmaf(v1.y, wgt, acc[5]);
        acc[6] = fmaf(v1.z, wgt, acc[6]); acc[7] = fmaf(v1.w, wgt, acc[7]);
    }
    // reduce across groups; wsum is replicated 8x per group (one head) -> scale by 1/8
    #pragma unroll
    for (int off = 8; off <= 32; off <<= 1) {
        wsum += __shfl_xor(wsum, off, 64);
        #pragma unroll
        for (int k = 0; k < 8; ++k) acc[k] += __shfl_xor(acc[k], off, 64);
    }
    if (g == 0 && ln < 5) {   // channels ln*8..ln*8+7, only 0..39 valid
        float inv8 = 0.125f / (wsum * 0.125f + 1e-16f);
        float4 o0, o1;
        o0.x = fmaf(acc[0], inv8, b2[ln * 8 + 0]);
        o0.y = fmaf(acc[1], inv8, b2[ln * 8 + 1]);
        o0.z = fmaf(acc[2], inv8, b2[ln * 8 + 2]);
        o0.w = fmaf(acc[3], inv8, b2[ln * 8 + 3]);
        o1.x = fmaf(acc[4], inv8, b2[ln * 8 + 4]);
        o1.y = fmaf(acc[5], inv8, b2[ln * 8 + 5]);
        o1.z = fmaf(acc[6], inv8, b2[ln * 8 + 6]);
        o1.w = fmaf(acc[7], inv8, b2[ln * 8 + 7]);
        *(float4*)&out[n * NC + ln * 8] = o0;
        *(float4*)&out[n * NC + ln * 8 + 4] = o1;
    }
}

// ---------------- launcher ----------------

extern "C" void kernel_launch(void* const* d_in, const int* in_sizes, int n_in,
                              void* d_out, int out_size, void* d_ws, size_t ws_size,
                              hipStream_t stream) {
    const float* x = (const float*)d_in[0];
    const int* ei = (const int*)d_in[1];   // harness passes integer inputs as int32
    const int* src = ei;
    const int* dst = ei + NE;
    const float* W1 = (const float*)d_in[2];
    const float* asrc1 = (const float*)d_in[3];
    const float* adst1 = (const float*)d_in[4];
    const float* b1 = (const float*)d_in[5];
    const float* W2 = (const float*)d_in[6];
    const float* asrc2 = (const float*)d_in[7];
    const float* adst2 = (const float*)d_in[8];
    const float* b2 = (const float*)d_in[9];
    float* out = (float*)d_out;

    // workspace layout (total 46,006,400 B):
    //   [0,12800000)          h1b bf16 [N][64]
    //   [12800000,16000000)   as1 fp32 [N][8]
    //   [16000000,19200000)   ad1 fp32 [N][8]
    //   [0,25600000)          h2p fp32 [N][64]   (aliases h1b/as1/ad1 -- dead after agg1)
    //   [25600000,38400000)   h1outb bf16 [N][64]; tmp int64 [NE] aliases (dead before agg1)
    //   [38400000,38800000)   as2 fp32 [N]
    //   [38800000,39200000)   ad2 fp32 [N]
    //   [39200000,45600000)   col int [NE]; cnt int [NBLK*NB] aliases (dead before scatter2)
    //   [45600000,46000128)   rowptr int [N+1, padded]
    //   [46000128,46003260)   btot int [NB]
    //   [46003264,46006400)   bbase int [NB+1, padded]
    char* ws = (char*)d_ws;
    unsigned short* h1b    = (unsigned short*)(ws + 0);
    float*          as1    = (float*)(ws + 12800000);
    float*          ad1    = (float*)(ws + 16000000);
    float*          h2p    = (float*)(ws + 0);
    unsigned short* h1outb = (unsigned short*)(ws + 25600000);
    long long*      tmp    = (long long*)(ws + 25600000);   // alias: dead before agg1 writes h1outb
    float*          as2    = (float*)(ws + 38400000);
    float*          ad2    = (float*)(ws + 38800000);
    int*            col    = (int*)(ws + 39200000);
    int*            cnt    = (int*)(ws + 39200000);          // alias: dead before scatter2 writes col
    int*            rowptr = (int*)(ws + 45600000);
    int*            btot   = (int*)(ws + 46000128);
    int*            bbase  = (int*)(ws + 46003264);

    bhist_k<<<NBLK, 256, 0, stream>>>(dst, cnt);
    bscan2_k<<<NB, 256, 0, stream>>>(cnt, btot);
    bscanB_k<<<1, 256, 0, stream>>>(btot, bbase);
    bplace_k<<<NBLK, 256, 0, stream>>>(src, dst, cnt, bbase, tmp);
    scatter2_k<<<NB, 256, 0, stream>>>(tmp, bbase, rowptr, col);

    gemm1_k<<<(NN + 63) / 64, 256, 0, stream>>>(x, W1, h1b);
    attn1_k<<<(NN * NH + 255) / 256, 256, 0, stream>>>(h1b, asrc1, adst1, as1, ad1);
    agg1_k<<<(NN + 3) / 4, 256, 0, stream>>>(h1b, as1, ad1, rowptr, col, b1, h1outb);

    gemm2_k<<<(NN + 63) / 64, 256, 0, stream>>>(h1outb, W2, h2p);
    attn2_k<<<(NN + 255) / 256, 256, 0, stream>>>(h2p, asrc2, adst2, as2, ad2);
    agg2_k<<<(NN + 3) / 4, 256, 0, stream>>>(h2p, as2, ad2, rowptr, col, b2, out);
}

// Round 10
// 230.305 us; speedup vs baseline: 3.6300x; 1.1505x over previous
//
#include <hip/hip_runtime.h>
#include <hip/hip_bf16.h>

#define NN 100000
#define NE 1600000
#define NF 256
#define NC 40
#define NH 8
#define D1 64
#define NEG 0.2f
#define BSHIFT 7
#define BSZ 128
#define NB ((NN + BSZ - 1) / BSZ)     // 782 buckets of 128 nodes
#define EPB 4096
#define NBLK ((NE + EPB - 1) / EPB)   // 391 edge blocks

typedef __attribute__((ext_vector_type(8))) short short8;
typedef __attribute__((ext_vector_type(4))) float f32x4;

static __device__ __forceinline__ float lrelu(float x) { return x > 0.f ? x : NEG * x; }

// unpack a uint holding 2 bf16 -> 2 floats
static __device__ __forceinline__ float2 bfx2(unsigned u) {
    union { unsigned q; float f; } a, b;
    a.q = u << 16;
    b.q = u & 0xFFFF0000u;
    return make_float2(a.f, b.f);
}

// pack 2 floats -> uint of 2 bf16, RNE
static __device__ __forceinline__ unsigned packbf2(float x, float y) {
    unsigned xu = __float_as_uint(x), yu = __float_as_uint(y);
    xu = (xu + 0x7FFFu + ((xu >> 16) & 1u)) >> 16;
    yu = (yu + 0x7FFFu + ((yu >> 16) & 1u)) >> 16;
    return xu | (yu << 16);
}

// single float -> bf16 (RNE)
static __device__ __forceinline__ unsigned short f2b(float x) {
    unsigned u = __float_as_uint(x);
    u = (u + 0x7FFFu + ((u >> 16) & 1u)) >> 16;
    return (unsigned short)u;
}

// ---------------- CSR build: deterministic multi-split (no global atomics) ----------------

__launch_bounds__(256)
__global__ void bhist_k(const int* __restrict__ dst, int* __restrict__ cnt) {
    __shared__ int hist[NB];
    int i = blockIdx.x, t = threadIdx.x;
    for (int b = t; b < NB; b += 256) hist[b] = 0;
    __syncthreads();
    int e0 = i * EPB;
    #pragma unroll
    for (int k = 0; k < EPB / 256; ++k) {
        int e = e0 + k * 256 + t;
        if (e < NE) atomicAdd(&hist[dst[e] >> BSHIFT], 1);
    }
    __syncthreads();
    for (int b = t; b < NB; b += 256) cnt[i * NB + b] = hist[b];
}

__launch_bounds__(256)
__global__ void bscan2_k(int* __restrict__ cnt, int* __restrict__ btot) {
    __shared__ int ps[256];
    int b = blockIdx.x, t = threadIdx.x;
    int i0 = 2 * t;
    int a = (i0 < NBLK) ? cnt[i0 * NB + b] : 0;
    int c = (i0 + 1 < NBLK) ? cnt[(i0 + 1) * NB + b] : 0;
    int s = a + c;
    ps[t] = s;
    __syncthreads();
    #pragma unroll
    for (int off = 1; off < 256; off <<= 1) {
        int x = (t >= off) ? ps[t - off] : 0;
        __syncthreads();
        ps[t] += x;
        __syncthreads();
    }
    int ex = ps[t] - s;
    if (i0 < NBLK) cnt[i0 * NB + b] = ex;
    if (i0 + 1 < NBLK) cnt[(i0 + 1) * NB + b] = ex + a;
    if (t == 255) btot[b] = ps[255];
}

__launch_bounds__(256)
__global__ void bscanB_k(const int* __restrict__ btot, int* __restrict__ bbase) {
    __shared__ int ps[256];
    int t = threadIdx.x;
    int j0 = 4 * t;
    int v[4]; int s = 0;
    #pragma unroll
    for (int k = 0; k < 4; ++k) { v[k] = (j0 + k < NB) ? btot[j0 + k] : 0; s += v[k]; }
    ps[t] = s;
    __syncthreads();
    #pragma unroll
    for (int off = 1; off < 256; off <<= 1) {
        int x = (t >= off) ? ps[t - off] : 0;
        __syncthreads();
        ps[t] += x;
        __syncthreads();
    }
    int run = ps[t] - s;
    #pragma unroll
    for (int k = 0; k < 4; ++k) { if (j0 + k < NB) bbase[j0 + k] = run; run += v[k]; }
    if (t == 0) bbase[NB] = NE;
}

__launch_bounds__(256)
__global__ void bplace_k(const int* __restrict__ src, const int* __restrict__ dst,
                         const int* __restrict__ cnt, const int* __restrict__ bbase,
                         long long* __restrict__ tmp) {
    __shared__ int loff[NB];
    int i = blockIdx.x, t = threadIdx.x;
    for (int b = t; b < NB; b += 256) loff[b] = bbase[b] + cnt[i * NB + b];
    __syncthreads();
    int e0 = i * EPB;
    #pragma unroll
    for (int k = 0; k < EPB / 256; ++k) {
        int e = e0 + k * 256 + t;
        if (e < NE) {
            int d = dst[e];
            int p = atomicAdd(&loff[d >> BSHIFT], 1);
            tmp[p] = ((long long)d << 32) | (unsigned)src[e];
        }
    }
}

__launch_bounds__(256)
__global__ void scatter2_k(const long long* __restrict__ tmp, const int* __restrict__ bbase,
                           int* __restrict__ rowptr, int* __restrict__ col) {
    __shared__ int lcnt[BSZ];
    __shared__ int lrow[BSZ];
    __shared__ int ls[BSZ];
    int b = blockIdx.x, t = threadIdx.x;
    int n0 = b << BSHIFT;
    if (t < BSZ) lcnt[t] = 0;
    __syncthreads();
    int beg = bbase[b], end = bbase[b + 1];
    for (int p = beg + t; p < end; p += 256) {
        int d = (int)(tmp[p] >> 32);
        atomicAdd(&lcnt[d - n0], 1);
    }
    __syncthreads();
    if (t < BSZ) ls[t] = lcnt[t];
    __syncthreads();
    #pragma unroll
    for (int off = 1; off < BSZ; off <<= 1) {
        int x = 0;
        if (t < BSZ && t >= off) x = ls[t - off];
        __syncthreads();
        if (t < BSZ) ls[t] += x;
        __syncthreads();
    }
    if (t < BSZ) {
        int ex = ls[t] - lcnt[t];
        lrow[t] = beg + ex;
        if (n0 + t < NN) rowptr[n0 + t] = beg + ex;
        lcnt[t] = 0;
    }
    if (b == NB - 1 && t == 0) rowptr[NN] = NE;
    __syncthreads();
    for (int p = beg + t; p < end; p += 256) {
        long long v = tmp[p];
        int d = (int)(v >> 32);
        int s = (int)(v & 0xFFFFFFFFLL);
        int o = atomicAdd(&lcnt[d - n0], 1);
        col[lrow[d - n0] + o] = s;
    }
}

// ---------------- GEMM1 (MFMA): h1 = x @ W1  [100000,256]x[256,64] -> bf16 ----------------
// block = 4 waves, 128 rows x 64 cols. W1 staged once into LDS pre-swizzled into
// B-fragment order [kt(8)][ct(4)][lane(64)][8] bf16 (32KB) so each B-frag is one ds_read_b128.
// A-frags: row = l&15, k = kt*32 + (l>>4)*8 + j  (2x float4 from global, packed to bf16).
// C-frag layout (m89-verified): col = lane&15, row = (lane>>4)*4 + r.

__launch_bounds__(256)
__global__ void gemm1_k(const float* __restrict__ x, const float* __restrict__ W,
                        unsigned short* __restrict__ h1b) {
    __shared__ unsigned short wsw[8 * 4 * 64 * 8];   // 16384 bf16 = 32 KB
    int tid = threadIdx.x;
    int wid = tid >> 6, lane = tid & 63;
    int r0 = blockIdx.x * 128 + wid * 32;

    // stage W swizzled (once per block)
    #pragma unroll
    for (int it = 0; it < 16; ++it) {
        int idx4 = it * 256 + tid;          // 0..4095
        int k = idx4 >> 4;                  // 0..255
        int c0 = (idx4 & 15) * 4;
        float4 v = *(const float4*)&W[k * 64 + c0];
        int kt = k >> 5, kg = (k >> 3) & 3, kr = k & 7;
        float vv[4] = {v.x, v.y, v.z, v.w};
        #pragma unroll
        for (int j = 0; j < 4; ++j) {
            int c = c0 + j;
            int dest = (((kt * 4 + (c >> 4)) * 64) + kg * 16 + (c & 15)) * 8 + kr;
            wsw[dest] = f2b(vv[j]);
        }
    }
    __syncthreads();

    int arow0 = r0 + (lane & 15);          // row-tile 0 row for this lane
    int kg8 = (lane >> 4) * 8;
    f32x4 acc[2][4] = {};
    for (int kt = 0; kt < 8; ++kt) {
        short8 af[2];
        #pragma unroll
        for (int rt = 0; rt < 2; ++rt) {
            int row = arow0 + rt * 16;
            float4 v0 = make_float4(0.f, 0.f, 0.f, 0.f), v1 = v0;
            if (row < NN) {
                const float* px = &x[row * NF + kt * 32 + kg8];
                v0 = *(const float4*)px;
                v1 = *(const float4*)(px + 4);
            }
            unsigned p0 = packbf2(v0.x, v0.y), p1 = packbf2(v0.z, v0.w);
            unsigned p2 = packbf2(v1.x, v1.y), p3 = packbf2(v1.z, v1.w);
            af[rt][0] = (short)(p0 & 0xFFFF); af[rt][1] = (short)(p0 >> 16);
            af[rt][2] = (short)(p1 & 0xFFFF); af[rt][3] = (short)(p1 >> 16);
            af[rt][4] = (short)(p2 & 0xFFFF); af[rt][5] = (short)(p2 >> 16);
            af[rt][6] = (short)(p3 & 0xFFFF); af[rt][7] = (short)(p3 >> 16);
        }
        #pragma unroll
        for (int ct = 0; ct < 4; ++ct) {
            short8 bf = *(const short8*)&wsw[((kt * 4 + ct) * 64 + lane) * 8];
            acc[0][ct] = __builtin_amdgcn_mfma_f32_16x16x32_bf16(af[0], bf, acc[0][ct], 0, 0, 0);
            acc[1][ct] = __builtin_amdgcn_mfma_f32_16x16x32_bf16(af[1], bf, acc[1][ct], 0, 0, 0);
        }
    }

    // epilogue: C layout col=lane&15, row=(lane>>4)*4+r
    int ccol = lane & 15;
    int crow0 = r0 + (lane >> 4) * 4;
    #pragma unroll
    for (int rt = 0; rt < 2; ++rt) {
        #pragma unroll
        for (int r = 0; r < 4; ++r) {
            int grow = crow0 + rt * 16 + r;
            if (grow < NN) {
                #pragma unroll
                for (int ct = 0; ct < 4; ++ct)
                    h1b[grow * D1 + ct * 16 + ccol] = f2b(acc[rt][ct][r]);
            }
        }
    }
}

// ---------------- attention coefficients layer 1 ----------------

__global__ void attn1_k(const unsigned short* __restrict__ h1b, const float* __restrict__ asrc,
                        const float* __restrict__ adst,
                        float* __restrict__ as1, float* __restrict__ ad1) {
    int t = blockIdx.x * blockDim.x + threadIdx.x;
    if (t >= NN * NH) return;
    int n = t >> 3, h = t & 7;
    uint4 v = *(const uint4*)&h1b[n * D1 + h * 8];
    float hv[8];
    float2 p;
    p = bfx2(v.x); hv[0] = p.x; hv[1] = p.y;
    p = bfx2(v.y); hv[2] = p.x; hv[3] = p.y;
    p = bfx2(v.z); hv[4] = p.x; hv[5] = p.y;
    p = bfx2(v.w); hv[6] = p.x; hv[7] = p.y;
    float sa = 0.f, sd = 0.f;
    #pragma unroll
    for (int c = 0; c < 8; ++c) {
        sa = fmaf(hv[c], asrc[h * 8 + c], sa);
        sd = fmaf(hv[c], adst[h * 8 + c], sd);
    }
    as1[t] = sa;
    ad1[t] = sd;
}

// ---------------- aggregation layer 1: single fused pass, 8 edges in flight ----------------

__launch_bounds__(256)
__global__ void agg1_k(const unsigned short* __restrict__ h1b, const float* __restrict__ as1,
                       const float* __restrict__ ad1,
                       const int* __restrict__ rowptr, const int* __restrict__ col,
                       const float* __restrict__ b1, unsigned short* __restrict__ h1outb) {
    int n = blockIdx.x * 4 + (threadIdx.x >> 6);
    if (n >= NN) return;
    int lane = threadIdx.x & 63;
    int g = lane >> 3, ln = lane & 7;
    int row0 = rowptr[n];
    int d = rowptr[n + 1] - row0;
    float adh = ad1[n * 8 + ln];

    float acc[8] = {};
    float wsum = 0.f;
    for (int j = 0; j <= d; j += 8) {
        int jj = j + g;
        int s = (jj < d) ? col[row0 + jj] : n;   // virtual self-loop at jj==d
        float e = lrelu(as1[s * 8 + ln] + adh);
        float wgt = (jj <= d) ? __expf(e) : 0.f;
        wsum += wgt;
        uint4 hv = *(const uint4*)&h1b[s * D1 + ln * 8];
        float2 p;
        p = bfx2(hv.x); acc[0] = fmaf(p.x, wgt, acc[0]); acc[1] = fmaf(p.y, wgt, acc[1]);
        p = bfx2(hv.y); acc[2] = fmaf(p.x, wgt, acc[2]); acc[3] = fmaf(p.y, wgt, acc[3]);
        p = bfx2(hv.z); acc[4] = fmaf(p.x, wgt, acc[4]); acc[5] = fmaf(p.y, wgt, acc[5]);
        p = bfx2(hv.w); acc[6] = fmaf(p.x, wgt, acc[6]); acc[7] = fmaf(p.y, wgt, acc[7]);
    }
    #pragma unroll
    for (int off = 8; off <= 32; off <<= 1) {
        wsum += __shfl_xor(wsum, off, 64);
        #pragma unroll
        for (int k = 0; k < 8; ++k) acc[k] += __shfl_xor(acc[k], off, 64);
    }
    if (g == 0) {
        float inv = 1.f / (wsum + 1e-16f);
        unsigned u[4];
        #pragma unroll
        for (int k = 0; k < 4; ++k) {
            float v0 = fmaf(acc[2 * k], inv, b1[ln * 8 + 2 * k]);
            float v1 = fmaf(acc[2 * k + 1], inv, b1[ln * 8 + 2 * k + 1]);
            v0 = (v0 > 0.f) ? v0 : (__expf(v0) - 1.f);   // ELU
            v1 = (v1 > 0.f) ? v1 : (__expf(v1) - 1.f);
            u[k] = packbf2(v0, v1);
        }
        uint4 w = {u[0], u[1], u[2], u[3]};
        *(uint4*)&h1outb[n * D1 + ln * 8] = w;
    }
}

// ---------------- GEMM2: h2p = h1out @ W2, padded [N][64] (cols 40..63 = 0) ----------------

__launch_bounds__(256)
__global__ void gemm2_k(const unsigned short* __restrict__ h1outb, const float* __restrict__ W2,
                        float* __restrict__ h2p) {
    __shared__ float xs[64 * 68];
    __shared__ float ws[64 * 40];
    int r0 = blockIdx.x * 64;
    int tid = threadIdx.x;
    #pragma unroll
    for (int it = 0; it < 4; ++it) {
        int idx = tid + it * 256;       // 0..1023
        int row = idx >> 4;             // 0..63
        int q = (idx & 15) * 4;         // col quad base
        int gr = r0 + row;
        float f0 = 0.f, f1 = 0.f, f2 = 0.f, f3 = 0.f;
        if (gr < NN) {
            uint2 v = *(const uint2*)&h1outb[gr * D1 + q];
            float2 p0 = bfx2(v.x), p1 = bfx2(v.y);
            f0 = p0.x; f1 = p0.y; f2 = p1.x; f3 = p1.y;
        }
        xs[row * 68 + q] = f0;
        xs[row * 68 + q + 1] = f1;
        xs[row * 68 + q + 2] = f2;
        xs[row * 68 + q + 3] = f3;
    }
    #pragma unroll
    for (int it = 0; it < 10; ++it) {
        int idx = tid + it * 256;
        if (idx < 64 * 40) ws[idx] = W2[idx];
    }
    __syncthreads();
    int r = tid >> 2, q = tid & 3;
    float acc[10] = {};
    #pragma unroll 4
    for (int k = 0; k < 64; ++k) {
        float xv = xs[r * 68 + k];
        #pragma unroll
        for (int i = 0; i < 10; ++i)
            acc[i] = fmaf(xv, ws[k * 40 + q * 10 + i], acc[i]);
    }
    int gr = r0 + r;
    if (gr < NN) {
        #pragma unroll
        for (int i = 0; i < 10; ++i) h2p[gr * 64 + q * 10 + i] = acc[i];
    }
    // zero pad columns 40..63
    for (int idx = tid; idx < 64 * 24; idx += 256) {
        int row = idx / 24, c = 40 + idx % 24;
        int g2 = r0 + row;
        if (g2 < NN) h2p[g2 * 64 + c] = 0.f;
    }
}

// ---------------- attention coefficients layer 2 ----------------

__global__ void attn2_k(const float* __restrict__ h2p, const float* __restrict__ asrc,
                        const float* __restrict__ adst,
                        float* __restrict__ as2, float* __restrict__ ad2) {
    int n = blockIdx.x * blockDim.x + threadIdx.x;
    if (n >= NN) return;
    float sa = 0.f, sd = 0.f;
    #pragma unroll
    for (int c0 = 0; c0 < NC; c0 += 4) {
        float4 v = *(const float4*)&h2p[n * 64 + c0];
        float4 a = *(const float4*)&asrc[c0];
        float4 b = *(const float4*)&adst[c0];
        sa += v.x * a.x + v.y * a.y + v.z * a.z + v.w * a.w;
        sd += v.x * b.x + v.y * b.y + v.z * b.z + v.w * b.w;
    }
    as2[n] = sa;
    ad2[n] = sd;
}

// ---------------- aggregation layer 2: fused single pass, 8 edges in flight ----------------

__launch_bounds__(256)
__global__ void agg2_k(const float* __restrict__ h2p, const float* __restrict__ as2,
                       const float* __restrict__ ad2,
                       const int* __restrict__ rowptr, const int* __restrict__ col,
                       const float* __restrict__ b2, float* __restrict__ out) {
    int n = blockIdx.x * 4 + (threadIdx.x >> 6);
    if (n >= NN) return;
    int lane = threadIdx.x & 63;
    int g = lane >> 3, ln = lane & 7;
    int row0 = rowptr[n];
    int d = rowptr[n + 1] - row0;
    float adn = ad2[n];

    float acc[8] = {};
    float wsum = 0.f;
    for (int j = 0; j <= d; j += 8) {
        int jj = j + g;
        int s = (jj < d) ? col[row0 + jj] : n;
        float e = lrelu(as2[s] + adn);
        float wgt = (jj <= d) ? __expf(e) : 0.f;
        wsum += wgt;
        float4 v0 = *(const float4*)&h2p[s * 64 + ln * 8];
        float4 v1 = *(const float4*)&h2p[s * 64 + ln * 8 + 4];
        acc[0] = fmaf(v0.x, wgt, acc[0]); acc[1] = fmaf(v0.y, wgt, acc[1]);
        acc[2] = fmaf(v0.z, wgt, acc[2]); acc[3] = fmaf(v0.w, wgt, acc[3]);
        acc[4] = fmaf(v1.x, wgt, acc[4]); acc[5] = fmaf(v1.y, wgt, acc[5]);
        acc[6] = fmaf(v1.z, wgt, acc[6]); acc[7] = fmaf(v1.w, wgt, acc[7]);
    }
    // reduce across groups; wsum is replicated 8x per group (one head) -> scale by 1/8
    #pragma unroll
    for (int off = 8; off <= 32; off <<= 1) {
        wsum += __shfl_xor(wsum, off, 64);
        #pragma unroll
        for (int k = 0; k < 8; ++k) acc[k] += __shfl_xor(acc[k], off, 64);
    }
    if (g == 0 && ln < 5) {   // channels ln*8..ln*8+7, only 0..39 valid
        float inv8 = 0.125f / (wsum * 0.125f + 1e-16f);
        float4 o0, o1;
        o0.x = fmaf(acc[0], inv8, b2[ln * 8 + 0]);
        o0.y = fmaf(acc[1], inv8, b2[ln * 8 + 1]);
        o0.z = fmaf(acc[2], inv8, b2[ln * 8 + 2]);
        o0.w = fmaf(acc[3], inv8, b2[ln * 8 + 3]);
        o1.x = fmaf(acc[4], inv8, b2[ln * 8 + 4]);
        o1.y = fmaf(acc[5], inv8, b2[ln * 8 + 5]);
        o1.z = fmaf(acc[6], inv8, b2[ln * 8 + 6]);
        o1.w = fmaf(acc[7], inv8, b2[ln * 8 + 7]);
        *(float4*)&out[n * NC + ln * 8] = o0;
        *(float4*)&out[n * NC + ln * 8 + 4] = o1;
    }
}

// ---------------- launcher ----------------

extern "C" void kernel_launch(void* const* d_in, const int* in_sizes, int n_in,
                              void* d_out, int out_size, void* d_ws, size_t ws_size,
                              hipStream_t stream) {
    const float* x = (const float*)d_in[0];
    const int* ei = (const int*)d_in[1];   // harness passes integer inputs as int32
    const int* src = ei;
    const int* dst = ei + NE;
    const float* W1 = (const float*)d_in[2];
    const float* asrc1 = (const float*)d_in[3];
    const float* adst1 = (const float*)d_in[4];
    const float* b1 = (const float*)d_in[5];
    const float* W2 = (const float*)d_in[6];
    const float* asrc2 = (const float*)d_in[7];
    const float* adst2 = (const float*)d_in[8];
    const float* b2 = (const float*)d_in[9];
    float* out = (float*)d_out;

    // workspace layout (total 46,006,400 B):
    //   [0,12800000)          h1b bf16 [N][64]
    //   [12800000,16000000)   as1 fp32 [N][8]
    //   [16000000,19200000)   ad1 fp32 [N][8]
    //   [0,25600000)          h2p fp32 [N][64]   (aliases h1b/as1/ad1 -- dead after agg1)
    //   [25600000,38400000)   h1outb bf16 [N][64]; tmp int64 [NE] aliases (dead before agg1)
    //   [38400000,38800000)   as2 fp32 [N]
    //   [38800000,39200000)   ad2 fp32 [N]
    //   [39200000,45600000)   col int [NE]; cnt int [NBLK*NB] aliases (dead before scatter2)
    //   [45600000,46000128)   rowptr int [N+1, padded]
    //   [46000128,46003260)   btot int [NB]
    //   [46003264,46006400)   bbase int [NB+1, padded]
    char* ws = (char*)d_ws;
    unsigned short* h1b    = (unsigned short*)(ws + 0);
    float*          as1    = (float*)(ws + 12800000);
    float*          ad1    = (float*)(ws + 16000000);
    float*          h2p    = (float*)(ws + 0);
    unsigned short* h1outb = (unsigned short*)(ws + 25600000);
    long long*      tmp    = (long long*)(ws + 25600000);   // alias: dead before agg1 writes h1outb
    float*          as2    = (float*)(ws + 38400000);
    float*          ad2    = (float*)(ws + 38800000);
    int*            col    = (int*)(ws + 39200000);
    int*            cnt    = (int*)(ws + 39200000);          // alias: dead before scatter2 writes col
    int*            rowptr = (int*)(ws + 45600000);
    int*            btot   = (int*)(ws + 46000128);
    int*            bbase  = (int*)(ws + 46003264);

    bhist_k<<<NBLK, 256, 0, stream>>>(dst, cnt);
    bscan2_k<<<NB, 256, 0, stream>>>(cnt, btot);
    bscanB_k<<<1, 256, 0, stream>>>(btot, bbase);
    bplace_k<<<NBLK, 256, 0, stream>>>(src, dst, cnt, bbase, tmp);
    scatter2_k<<<NB, 256, 0, stream>>>(tmp, bbase, rowptr, col);

    gemm1_k<<<(NN + 127) / 128, 256, 0, stream>>>(x, W1, h1b);
    attn1_k<<<(NN * NH + 255) / 256, 256, 0, stream>>>(h1b, asrc1, adst1, as1, ad1);
    agg1_k<<<(NN + 3) / 4, 256, 0, stream>>>(h1b, as1, ad1, rowptr, col, b1, h1outb);

    gemm2_k<<<(NN + 63) / 64, 256, 0, stream>>>(h1outb, W2, h2p);
    attn2_k<<<(NN + 255) / 256, 256, 0, stream>>>(h2p, asrc2, adst2, as2, ad2);
    agg2_k<<<(NN + 3) / 4, 256, 0, stream>>>(h2p, as2, ad2, rowptr, col, b2, out);
}

// Round 12
// 212.835 us; speedup vs baseline: 3.9279x; 1.0821x over previous
//
#include <hip/hip_runtime.h>
#include <hip/hip_bf16.h>

#define NN 100000
#define NE 1600000
#define NF 256
#define NC 40
#define NH 8
#define D1 64
#define NEG 0.2f
#define BSHIFT 7
#define BSZ 128
#define NB ((NN + BSZ - 1) / BSZ)     // 782 buckets of 128 nodes
#define EPB 4096
#define NBLK ((NE + EPB - 1) / EPB)   // 391 edge blocks

typedef __attribute__((ext_vector_type(8))) short short8;
typedef __attribute__((ext_vector_type(4))) float f32x4;

static __device__ __forceinline__ float lrelu(float x) { return x > 0.f ? x : NEG * x; }

static __device__ __forceinline__ float2 bfx2(unsigned u) {
    union { unsigned q; float f; } a, b;
    a.q = u << 16;
    b.q = u & 0xFFFF0000u;
    return make_float2(a.f, b.f);
}

static __device__ __forceinline__ unsigned packbf2(float x, float y) {
    unsigned xu = __float_as_uint(x), yu = __float_as_uint(y);
    xu = (xu + 0x7FFFu + ((xu >> 16) & 1u)) >> 16;
    yu = (yu + 0x7FFFu + ((yu >> 16) & 1u)) >> 16;
    return xu | (yu << 16);
}

static __device__ __forceinline__ unsigned short f2b(float x) {
    unsigned u = __float_as_uint(x);
    u = (u + 0x7FFFu + ((u >> 16) & 1u)) >> 16;
    return (unsigned short)u;
}

// ---------------- CSR build: deterministic multi-split (no global atomics) ----------------

__launch_bounds__(256)
__global__ void bhist_k(const int* __restrict__ dst, int* __restrict__ cnt) {
    __shared__ int hist[NB];
    int i = blockIdx.x, t = threadIdx.x;
    for (int b = t; b < NB; b += 256) hist[b] = 0;
    __syncthreads();
    int e0 = i * EPB;
    #pragma unroll
    for (int k = 0; k < EPB / 256; ++k) {
        int e = e0 + k * 256 + t;
        if (e < NE) atomicAdd(&hist[dst[e] >> BSHIFT], 1);
    }
    __syncthreads();
    for (int b = t; b < NB; b += 256) cnt[i * NB + b] = hist[b];
}

__launch_bounds__(256)
__global__ void bscan2_k(int* __restrict__ cnt, int* __restrict__ btot) {
    __shared__ int ps[256];
    int b = blockIdx.x, t = threadIdx.x;
    int i0 = 2 * t;
    int a = (i0 < NBLK) ? cnt[i0 * NB + b] : 0;
    int c = (i0 + 1 < NBLK) ? cnt[(i0 + 1) * NB + b] : 0;
    int s = a + c;
    ps[t] = s;
    __syncthreads();
    #pragma unroll
    for (int off = 1; off < 256; off <<= 1) {
        int x = (t >= off) ? ps[t - off] : 0;
        __syncthreads();
        ps[t] += x;
        __syncthreads();
    }
    int ex = ps[t] - s;
    if (i0 < NBLK) cnt[i0 * NB + b] = ex;
    if (i0 + 1 < NBLK) cnt[(i0 + 1) * NB + b] = ex + a;
    if (t == 255) btot[b] = ps[255];
}

__launch_bounds__(256)
__global__ void bscanB_k(const int* __restrict__ btot, int* __restrict__ bbase) {
    __shared__ int ps[256];
    int t = threadIdx.x;
    int j0 = 4 * t;
    int v[4]; int s = 0;
    #pragma unroll
    for (int k = 0; k < 4; ++k) { v[k] = (j0 + k < NB) ? btot[j0 + k] : 0; s += v[k]; }
    ps[t] = s;
    __syncthreads();
    #pragma unroll
    for (int off = 1; off < 256; off <<= 1) {
        int x = (t >= off) ? ps[t - off] : 0;
        __syncthreads();
        ps[t] += x;
        __syncthreads();
    }
    int run = ps[t] - s;
    #pragma unroll
    for (int k = 0; k < 4; ++k) { if (j0 + k < NB) bbase[j0 + k] = run; run += v[k]; }
    if (t == 0) bbase[NB] = NE;
}

__launch_bounds__(256)
__global__ void bplace_k(const int* __restrict__ src, const int* __restrict__ dst,
                         const int* __restrict__ cnt, const int* __restrict__ bbase,
                         long long* __restrict__ tmp) {
    __shared__ int loff[NB];
    int i = blockIdx.x, t = threadIdx.x;
    for (int b = t; b < NB; b += 256) loff[b] = bbase[b] + cnt[i * NB + b];
    __syncthreads();
    int e0 = i * EPB;
    #pragma unroll
    for (int k = 0; k < EPB / 256; ++k) {
        int e = e0 + k * 256 + t;
        if (e < NE) {
            int d = dst[e];
            int p = atomicAdd(&loff[d >> BSHIFT], 1);
            tmp[p] = ((long long)d << 32) | (unsigned)src[e];
        }
    }
}

__launch_bounds__(256)
__global__ void scatter2_k(const long long* __restrict__ tmp, const int* __restrict__ bbase,
                           int* __restrict__ rowptr, int* __restrict__ col) {
    __shared__ int lcnt[BSZ];
    __shared__ int lrow[BSZ];
    __shared__ int ls[BSZ];
    int b = blockIdx.x, t = threadIdx.x;
    int n0 = b << BSHIFT;
    if (t < BSZ) lcnt[t] = 0;
    __syncthreads();
    int beg = bbase[b], end = bbase[b + 1];
    for (int p = beg + t; p < end; p += 256) {
        int d = (int)(tmp[p] >> 32);
        atomicAdd(&lcnt[d - n0], 1);
    }
    __syncthreads();
    if (t < BSZ) ls[t] = lcnt[t];
    __syncthreads();
    #pragma unroll
    for (int off = 1; off < BSZ; off <<= 1) {
        int x = 0;
        if (t < BSZ && t >= off) x = ls[t - off];
        __syncthreads();
        if (t < BSZ) ls[t] += x;
        __syncthreads();
    }
    if (t < BSZ) {
        int ex = ls[t] - lcnt[t];
        lrow[t] = beg + ex;
        if (n0 + t < NN) rowptr[n0 + t] = beg + ex;
        lcnt[t] = 0;
    }
    if (b == NB - 1 && t == 0) rowptr[NN] = NE;
    __syncthreads();
    for (int p = beg + t; p < end; p += 256) {
        long long v = tmp[p];
        int d = (int)(v >> 32);
        int s = (int)(v & 0xFFFFFFFFLL);
        int o = atomicAdd(&lcnt[d - n0], 1);
        col[lrow[d - n0] + o] = s;
    }
}

// ---------------- GEMM1 (MFMA): h1 = x @ W1  [100000,256]x[256,64] -> bf16 ----------------

__launch_bounds__(256)
__global__ void gemm1_k(const float* __restrict__ x, const float* __restrict__ W,
                        unsigned short* __restrict__ h1b) {
    __shared__ unsigned short wsw[8 * 4 * 64 * 8];   // 16384 bf16 = 32 KB
    int tid = threadIdx.x;
    int wid = tid >> 6, lane = tid & 63;
    int r0 = blockIdx.x * 128 + wid * 32;

    #pragma unroll
    for (int it = 0; it < 16; ++it) {
        int idx4 = it * 256 + tid;
        int k = idx4 >> 4;
        int c0 = (idx4 & 15) * 4;
        float4 v = *(const float4*)&W[k * 64 + c0];
        int kt = k >> 5, kg = (k >> 3) & 3, kr = k & 7;
        float vv[4] = {v.x, v.y, v.z, v.w};
        #pragma unroll
        for (int j = 0; j < 4; ++j) {
            int c = c0 + j;
            int dest = (((kt * 4 + (c >> 4)) * 64) + kg * 16 + (c & 15)) * 8 + kr;
            wsw[dest] = f2b(vv[j]);
        }
    }
    __syncthreads();

    int arow0 = r0 + (lane & 15);
    int kg8 = (lane >> 4) * 8;
    f32x4 acc[2][4] = {};
    for (int kt = 0; kt < 8; ++kt) {
        short8 af[2];
        #pragma unroll
        for (int rt = 0; rt < 2; ++rt) {
            int row = arow0 + rt * 16;
            float4 v0 = make_float4(0.f, 0.f, 0.f, 0.f), v1 = v0;
            if (row < NN) {
                const float* px = &x[row * NF + kt * 32 + kg8];
                v0 = *(const float4*)px;
                v1 = *(const float4*)(px + 4);
            }
            unsigned p0 = packbf2(v0.x, v0.y), p1 = packbf2(v0.z, v0.w);
            unsigned p2 = packbf2(v1.x, v1.y), p3 = packbf2(v1.z, v1.w);
            af[rt][0] = (short)(p0 & 0xFFFF); af[rt][1] = (short)(p0 >> 16);
            af[rt][2] = (short)(p1 & 0xFFFF); af[rt][3] = (short)(p1 >> 16);
            af[rt][4] = (short)(p2 & 0xFFFF); af[rt][5] = (short)(p2 >> 16);
            af[rt][6] = (short)(p3 & 0xFFFF); af[rt][7] = (short)(p3 >> 16);
        }
        #pragma unroll
        for (int ct = 0; ct < 4; ++ct) {
            short8 bf = *(const short8*)&wsw[((kt * 4 + ct) * 64 + lane) * 8];
            acc[0][ct] = __builtin_amdgcn_mfma_f32_16x16x32_bf16(af[0], bf, acc[0][ct], 0, 0, 0);
            acc[1][ct] = __builtin_amdgcn_mfma_f32_16x16x32_bf16(af[1], bf, acc[1][ct], 0, 0, 0);
        }
    }

    int ccol = lane & 15;
    int crow0 = r0 + (lane >> 4) * 4;
    #pragma unroll
    for (int rt = 0; rt < 2; ++rt) {
        #pragma unroll
        for (int r = 0; r < 4; ++r) {
            int grow = crow0 + rt * 16 + r;
            if (grow < NN) {
                #pragma unroll
                for (int ct = 0; ct < 4; ++ct)
                    h1b[grow * D1 + ct * 16 + ccol] = f2b(acc[rt][ct][r]);
            }
        }
    }
}

// ---------------- attention coefficients layer 1 ----------------

__global__ void attn1_k(const unsigned short* __restrict__ h1b, const float* __restrict__ asrc,
                        const float* __restrict__ adst,
                        float* __restrict__ as1, float* __restrict__ ad1) {
    int t = blockIdx.x * blockDim.x + threadIdx.x;
    if (t >= NN * NH) return;
    int n = t >> 3, h = t & 7;
    uint4 v = *(const uint4*)&h1b[n * D1 + h * 8];
    float hv[8];
    float2 p;
    p = bfx2(v.x); hv[0] = p.x; hv[1] = p.y;
    p = bfx2(v.y); hv[2] = p.x; hv[3] = p.y;
    p = bfx2(v.z); hv[4] = p.x; hv[5] = p.y;
    p = bfx2(v.w); hv[6] = p.x; hv[7] = p.y;
    float sa = 0.f, sd = 0.f;
    #pragma unroll
    for (int c = 0; c < 8; ++c) {
        sa = fmaf(hv[c], asrc[h * 8 + c], sa);
        sd = fmaf(hv[c], adst[h * 8 + c], sd);
    }
    as1[t] = sa;
    ad1[t] = sd;
}

// ---------------- aggregation layer 1: single fused pass, 8 edges in flight ----------------

__launch_bounds__(256)
__global__ void agg1_k(const unsigned short* __restrict__ h1b, const float* __restrict__ as1,
                       const float* __restrict__ ad1,
                       const int* __restrict__ rowptr, const int* __restrict__ col,
                       const float* __restrict__ b1, unsigned short* __restrict__ h1outb) {
    int n = blockIdx.x * 4 + (threadIdx.x >> 6);
    if (n >= NN) return;
    int lane = threadIdx.x & 63;
    int g = lane >> 3, ln = lane & 7;
    int row0 = rowptr[n];
    int d = rowptr[n + 1] - row0;
    float adh = ad1[n * 8 + ln];

    float acc[8] = {};
    float wsum = 0.f;
    for (int j = 0; j <= d; j += 8) {
        int jj = j + g;
        int s = (jj < d) ? col[row0 + jj] : n;   // virtual self-loop at jj==d
        float e = lrelu(as1[s * 8 + ln] + adh);
        float wgt = (jj <= d) ? __expf(e) : 0.f;
        wsum += wgt;
        uint4 hv = *(const uint4*)&h1b[s * D1 + ln * 8];
        float2 p;
        p = bfx2(hv.x); acc[0] = fmaf(p.x, wgt, acc[0]); acc[1] = fmaf(p.y, wgt, acc[1]);
        p = bfx2(hv.y); acc[2] = fmaf(p.x, wgt, acc[2]); acc[3] = fmaf(p.y, wgt, acc[3]);
        p = bfx2(hv.z); acc[4] = fmaf(p.x, wgt, acc[4]); acc[5] = fmaf(p.y, wgt, acc[5]);
        p = bfx2(hv.w); acc[6] = fmaf(p.x, wgt, acc[6]); acc[7] = fmaf(p.y, wgt, acc[7]);
    }
    #pragma unroll
    for (int off = 8; off <= 32; off <<= 1) {
        wsum += __shfl_xor(wsum, off, 64);
        #pragma unroll
        for (int k = 0; k < 8; ++k) acc[k] += __shfl_xor(acc[k], off, 64);
    }
    if (g == 0) {
        float inv = 1.f / (wsum + 1e-16f);
        unsigned u[4];
        #pragma unroll
        for (int k = 0; k < 4; ++k) {
            float v0 = fmaf(acc[2 * k], inv, b1[ln * 8 + 2 * k]);
            float v1 = fmaf(acc[2 * k + 1], inv, b1[ln * 8 + 2 * k + 1]);
            v0 = (v0 > 0.f) ? v0 : (__expf(v0) - 1.f);   // ELU
            v1 = (v1 > 0.f) ? v1 : (__expf(v1) - 1.f);
            u[k] = packbf2(v0, v1);
        }
        uint4 w = {u[0], u[1], u[2], u[3]};
        *(uint4*)&h1outb[n * D1 + ln * 8] = w;
    }
}

// ---------------- attention coefficients layer 2 (from h1out via W2-folded vectors) ----------------
// as2[n] = h2[n].asrc2 = h1out[n].(W2@asrc2); same for ad2. Exact algebra, no h2 needed.

__launch_bounds__(256)
__global__ void attn2_k(const unsigned short* __restrict__ h1outb, const float* __restrict__ W2,
                        const float* __restrict__ asrc, const float* __restrict__ adst,
                        float* __restrict__ as2, float* __restrict__ ad2) {
    __shared__ float w2a[64], w2d[64];
    int tid = threadIdx.x;
    if (tid < 128) {
        int c = tid & 63;
        const float* av = (tid < 64) ? asrc : adst;
        float s = 0.f;
        #pragma unroll
        for (int j = 0; j < NC; ++j) s = fmaf(W2[c * NC + j], av[j], s);
        if (tid < 64) w2a[c] = s; else w2d[c] = s;
    }
    __syncthreads();
    int n = blockIdx.x * 256 + tid;
    if (n >= NN) return;
    float sa = 0.f, sd = 0.f;
    #pragma unroll
    for (int q = 0; q < 8; ++q) {
        uint4 v = *(const uint4*)&h1outb[n * D1 + q * 8];
        int c0 = q * 8;
        float2 p;
        p = bfx2(v.x);
        sa = fmaf(p.x, w2a[c0], sa);     sd = fmaf(p.x, w2d[c0], sd);
        sa = fmaf(p.y, w2a[c0 + 1], sa); sd = fmaf(p.y, w2d[c0 + 1], sd);
        p = bfx2(v.y);
        sa = fmaf(p.x, w2a[c0 + 2], sa); sd = fmaf(p.x, w2d[c0 + 2], sd);
        sa = fmaf(p.y, w2a[c0 + 3], sa); sd = fmaf(p.y, w2d[c0 + 3], sd);
        p = bfx2(v.z);
        sa = fmaf(p.x, w2a[c0 + 4], sa); sd = fmaf(p.x, w2d[c0 + 4], sd);
        sa = fmaf(p.y, w2a[c0 + 5], sa); sd = fmaf(p.y, w2d[c0 + 5], sd);
        p = bfx2(v.w);
        sa = fmaf(p.x, w2a[c0 + 6], sa); sd = fmaf(p.x, w2d[c0 + 6], sd);
        sa = fmaf(p.y, w2a[c0 + 7], sa); sd = fmaf(p.y, w2d[c0 + 7], sd);
    }
    as2[n] = sa;
    ad2[n] = sd;
}

// ---------------- aggregation layer 2: aggregate h1out (bf16) -> z, W2 applied after ----------------
// out[n] = (sum_s alpha * h1out[s]) @ W2 + b2, so aggregate the 64-ch bf16 h1out (128B/edge).

__launch_bounds__(256)
__global__ void agg2_k(const unsigned short* __restrict__ h1outb, const float* __restrict__ as2,
                       const float* __restrict__ ad2,
                       const int* __restrict__ rowptr, const int* __restrict__ col,
                       unsigned short* __restrict__ zb) {
    int n = blockIdx.x * 4 + (threadIdx.x >> 6);
    if (n >= NN) return;
    int lane = threadIdx.x & 63;
    int g = lane >> 3, ln = lane & 7;
    int row0 = rowptr[n];
    int d = rowptr[n + 1] - row0;
    float adn = ad2[n];

    float acc[8] = {};
    float wsum = 0.f;
    for (int j = 0; j <= d; j += 8) {
        int jj = j + g;
        int s = (jj < d) ? col[row0 + jj] : n;
        float e = lrelu(as2[s] + adn);
        float wgt = (jj <= d) ? __expf(e) : 0.f;
        wsum += wgt;
        uint4 hv = *(const uint4*)&h1outb[s * D1 + ln * 8];
        float2 p;
        p = bfx2(hv.x); acc[0] = fmaf(p.x, wgt, acc[0]); acc[1] = fmaf(p.y, wgt, acc[1]);
        p = bfx2(hv.y); acc[2] = fmaf(p.x, wgt, acc[2]); acc[3] = fmaf(p.y, wgt, acc[3]);
        p = bfx2(hv.z); acc[4] = fmaf(p.x, wgt, acc[4]); acc[5] = fmaf(p.y, wgt, acc[5]);
        p = bfx2(hv.w); acc[6] = fmaf(p.x, wgt, acc[6]); acc[7] = fmaf(p.y, wgt, acc[7]);
    }
    // butterfly over lane bits 3..5 (the g axis) -> exact sums (wsum counted once per edge)
    #pragma unroll
    for (int off = 8; off <= 32; off <<= 1) {
        wsum += __shfl_xor(wsum, off, 64);
        #pragma unroll
        for (int k = 0; k < 8; ++k) acc[k] += __shfl_xor(acc[k], off, 64);
    }
    if (g == 0) {
        float inv = 1.f / (wsum + 1e-16f);
        unsigned u[4];
        #pragma unroll
        for (int k = 0; k < 4; ++k)
            u[k] = packbf2(acc[2 * k] * inv, acc[2 * k + 1] * inv);
        uint4 w = {u[0], u[1], u[2], u[3]};
        *(uint4*)&zb[n * D1 + ln * 8] = w;
    }
}

// ---------------- GEMM2: out = z @ W2 + b2   [100000,64]x[64,40] -> d_out ----------------

__launch_bounds__(256)
__global__ void gemm2_k(const unsigned short* __restrict__ zb, const float* __restrict__ W2,
                        const float* __restrict__ b2, float* __restrict__ out) {
    __shared__ float xs[64 * 68];
    __shared__ float wsm[64 * 40];
    __shared__ float bs[40];
    int r0 = blockIdx.x * 64;
    int tid = threadIdx.x;
    #pragma unroll
    for (int it = 0; it < 4; ++it) {
        int idx = tid + it * 256;       // 0..1023
        int row = idx >> 4;             // 0..63
        int q = (idx & 15) * 4;         // col quad base
        int gr = r0 + row;
        float f0 = 0.f, f1 = 0.f, f2 = 0.f, f3 = 0.f;
        if (gr < NN) {
            uint2 v = *(const uint2*)&zb[gr * D1 + q];
            float2 p0 = bfx2(v.x), p1 = bfx2(v.y);
            f0 = p0.x; f1 = p0.y; f2 = p1.x; f3 = p1.y;
        }
        xs[row * 68 + q] = f0;
        xs[row * 68 + q + 1] = f1;
        xs[row * 68 + q + 2] = f2;
        xs[row * 68 + q + 3] = f3;
    }
    #pragma unroll
    for (int it = 0; it < 10; ++it) {
        int idx = tid + it * 256;
        if (idx < 64 * 40) wsm[idx] = W2[idx];
    }
    if (tid < 40) bs[tid] = b2[tid];
    __syncthreads();
    int r = tid >> 2, q = tid & 3;
    float acc[10] = {};
    #pragma unroll 4
    for (int k = 0; k < 64; ++k) {
        float xv = xs[r * 68 + k];
        #pragma unroll
        for (int i = 0; i < 10; ++i)
            acc[i] = fmaf(xv, wsm[k * 40 + q * 10 + i], acc[i]);
    }
    int gr = r0 + r;
    if (gr < NN) {
        #pragma unroll
        for (int i = 0; i < 10; ++i) out[gr * NC + q * 10 + i] = acc[i] + bs[q * 10 + i];
    }
}

// ---------------- launcher ----------------

extern "C" void kernel_launch(void* const* d_in, const int* in_sizes, int n_in,
                              void* d_out, int out_size, void* d_ws, size_t ws_size,
                              hipStream_t stream) {
    const float* x = (const float*)d_in[0];
    const int* ei = (const int*)d_in[1];   // harness passes integer inputs as int32
    const int* src = ei;
    const int* dst = ei + NE;
    const float* W1 = (const float*)d_in[2];
    const float* asrc1 = (const float*)d_in[3];
    const float* adst1 = (const float*)d_in[4];
    const float* b1 = (const float*)d_in[5];
    const float* W2 = (const float*)d_in[6];
    const float* asrc2 = (const float*)d_in[7];
    const float* adst2 = (const float*)d_in[8];
    const float* b2 = (const float*)d_in[9];
    float* out = (float*)d_out;

    // workspace layout (total 46,006,400 B):
    //   [0,12800000)          h1b bf16 [N][64]; zb bf16 [N][64] aliases (h1b dead after agg1)
    //   [12800000,16000000)   as1 fp32 [N][8]
    //   [16000000,19200000)   ad1 fp32 [N][8]
    //   [25600000,38400000)   h1outb bf16 [N][64]; tmp int64 [NE] aliases (dead before agg1)
    //   [38400000,38800000)   as2 fp32 [N]
    //   [38800000,39200000)   ad2 fp32 [N]
    //   [39200000,45600000)   col int [NE]; cnt int [NBLK*NB] aliases (dead before scatter2)
    //   [45600000,46000128)   rowptr int [N+1, padded]
    //   [46000128,46003260)   btot int [NB]
    //   [46003264,46006400)   bbase int [NB+1, padded]
    char* ws = (char*)d_ws;
    unsigned short* h1b    = (unsigned short*)(ws + 0);
    unsigned short* zb     = (unsigned short*)(ws + 0);      // alias: h1b dead after agg1
    float*          as1    = (float*)(ws + 12800000);
    float*          ad1    = (float*)(ws + 16000000);
    unsigned short* h1outb = (unsigned short*)(ws + 25600000);
    long long*      tmp    = (long long*)(ws + 25600000);    // alias: dead before agg1 writes h1outb
    float*          as2    = (float*)(ws + 38400000);
    float*          ad2    = (float*)(ws + 38800000);
    int*            col    = (int*)(ws + 39200000);
    int*            cnt    = (int*)(ws + 39200000);          // alias: dead before scatter2 writes col
    int*            rowptr = (int*)(ws + 45600000);
    int*            btot   = (int*)(ws + 46000128);
    int*            bbase  = (int*)(ws + 46003264);

    bhist_k<<<NBLK, 256, 0, stream>>>(dst, cnt);
    bscan2_k<<<NB, 256, 0, stream>>>(cnt, btot);
    bscanB_k<<<1, 256, 0, stream>>>(btot, bbase);
    bplace_k<<<NBLK, 256, 0, stream>>>(src, dst, cnt, bbase, tmp);
    scatter2_k<<<NB, 256, 0, stream>>>(tmp, bbase, rowptr, col);

    gemm1_k<<<(NN + 127) / 128, 256, 0, stream>>>(x, W1, h1b);
    attn1_k<<<(NN * NH + 255) / 256, 256, 0, stream>>>(h1b, asrc1, adst1, as1, ad1);
    agg1_k<<<(NN + 3) / 4, 256, 0, stream>>>(h1b, as1, ad1, rowptr, col, b1, h1outb);

    attn2_k<<<(NN + 255) / 256, 256, 0, stream>>>(h1outb, W2, asrc2, adst2, as2, ad2);
    agg2_k<<<(NN + 3) / 4, 256, 0, stream>>>(h1outb, as2, ad2, rowptr, col, zb);
    gemm2_k<<<(NN + 63) / 64, 256, 0, stream>>>(zb, W2, b2, out);
}